// Round 8
// baseline (2098.430 us; speedup 1.0000x reference)
//
#include <hip/hip_runtime.h>
#include <hip/hip_bf16.h>
#include <stdint.h>

static constexpr int B_  = 32;
static constexpr int E_  = 256;
static constexpr int N_  = 512;    // 2E
static constexpr int C_  = 256;    // H*F
static constexpr int BN  = B_ * N_;
static constexpr int NODE_ELEMS = B_ * N_ * C_;          // 4,194,304
static constexpr int ADJ_ELEMS  = B_ * 14 * N_ * N_;     // 117,440,512

// ---------------- dtype-agnostic input conversion ----------------
struct ConvArgs {
  const void* src[14];
  void* dst[14];
  int n[14];
  int kind[14];   // 0 = float array, 1 = int array
};

__global__ __launch_bounds__(256) void k_conv2(ConvArgs a, const unsigned* fprobe,
                                               const unsigned* iprobe) {
  __shared__ int fk_s, ik_s;
  int t = threadIdx.x;
  if (t == 0) {
    int c_even = 0, c_lo = 0;
    for (int k = 0; k < 32; ++k) {
      unsigned w = fprobe[2 * k];
      unsigned e32 = (w >> 23) & 0xFFu;
      unsigned elo = (w >> 7) & 0xFFu;
      if (e32 >= 105u && e32 <= 135u) ++c_even;
      if (elo >= 105u && elo <= 135u) ++c_lo;
    }
    fk_s = (c_even < 16) ? 2 : ((c_lo >= 16) ? 1 : 0);   // 2=f64, 1=bf16, 0=f32
    int hi0 = 0;
    for (int k = 0; k < 32; ++k) if (iprobe[2 * k + 1] == 0u) ++hi0;
    ik_s = (hi0 >= 30) ? 1 : 0;                          // 1=i64, 0=i32
  }
  __syncthreads();
  int fk = fk_s, ik = ik_s;
  int arr = blockIdx.y;
  int n = a.n[arr], kind = a.kind[arr];
  for (int idx = blockIdx.x * 256 + t; idx < n; idx += gridDim.x * 256) {
    if (kind == 0) {
      float v;
      if (fk == 2) {
        v = (float)((const double*)a.src[arr])[idx];
      } else if (fk == 1) {
        unsigned short u = ((const unsigned short*)a.src[arr])[idx];
        union { unsigned u; float f; } c; c.u = (unsigned)u << 16; v = c.f;
      } else {
        v = ((const float*)a.src[arr])[idx];
      }
      ((float*)a.dst[arr])[idx] = v;
    } else {
      int v;
      if (ik == 1) v = (int)((const long long*)a.src[arr])[idx];
      else         v = ((const int*)a.src[arr])[idx];
      ((int*)a.dst[arr])[idx] = v;
    }
  }
}

// ---------------- node features: one thread per node ----------------
__global__ __launch_bounds__(256) void k_feat2(
    const int* __restrict__ player, const float* __restrict__ Ax, const float* __restrict__ Ay,
    const float* __restrict__ Bx, const float* __restrict__ By,
    const float* __restrict__ emb, const float* __restrict__ Wc, const float* __restrict__ bc,
    const float* __restrict__ Wm, const float* __restrict__ bm, float* __restrict__ x) {
  int id = blockIdx.x * 256 + threadIdx.x;   // b*512 + n
  if (id >= BN) return;
  int b = id >> 9, n = id & 511;
  int e = n >> 1, side = n & 1;
  float cx = side ? Bx[b * E_ + e] : Ax[b * E_ + e];
  float cy = side ? By[b * E_ + e] : Ay[b * E_ + e];
  int pid = player[b * 2 + side];
  float ct[32];
  for (int k = 0; k < 32; ++k)
    ct[k] = fmaxf(fmaf(cx, Wc[k], fmaf(cy, Wc[32 + k], bc[k])), 0.f);
  for (int o = 0; o < 64; ++o) {
    float acc = bm[o];
    for (int c = 0; c < 32; ++c) acc = fmaf(ct[c], Wm[c * 64 + o], acc);
    for (int c = 0; c < 32; ++c) acc = fmaf(emb[pid * 32 + c], Wm[(32 + c) * 64 + o], acc);
    x[(size_t)id * 64 + o] = acc;
  }
}

// ---------------- naive GEMM ----------------
__global__ __launch_bounds__(256) void k_gemm_naive(
    const float* __restrict__ x, const float* __restrict__ W, float* __restrict__ h, int K) {
  int idx = blockIdx.x * 256 + threadIdx.x;   // row*256 + col
  int row = idx >> 8, col = idx & 255;
  float acc = 0.f;
  for (int k = 0; k < K; ++k)
    acc = fmaf(x[(size_t)row * K + k], W[(size_t)k * 256 + col], acc);
  h[(size_t)idx] = acc;
}

// ---------------- scores ----------------
__global__ __launch_bounds__(256) void k_score(
    const float* __restrict__ h, const float* __restrict__ att,
    float* __restrict__ ss, float* __restrict__ sd) {
  int idx = blockIdx.x * 256 + threadIdx.x;   // (b*4+hd)*512 + n
  int n = idx & 511, hd = (idx >> 9) & 3, b = idx >> 11;
  const float* hrow = h + (size_t)(b * 512 + n) * 256 + hd * 64;
  float a1 = 0.f, a2 = 0.f;
  for (int f = 0; f < 64; ++f) {
    float v = hrow[f];
    a1 = fmaf(v, att[hd * 128 + f], a1);
    a2 = fmaf(v, att[hd * 128 + 64 + f], a2);
  }
  ss[idx] = a1; sd[idx] = a2;
}

// ---------------- full softmax row ----------------
__global__ __launch_bounds__(512) void k_attnrow(
    const float* __restrict__ ss, const float* __restrict__ sd, float* __restrict__ A) {
  int row = blockIdx.x;
  int i = row & 511, bh = row >> 9;
  int t = threadIdx.x;                 // = j
  int wv = t >> 6, l = t & 63;
  __shared__ float red[16];
  float s = ss[row] + sd[bh * 512 + t];
  float sc = fmaxf(s, 0.2f * s);       // LeakyReLU(0.2)
  float v = (t == i) ? -3e38f : sc;    // mask = (i != j)
  #pragma unroll
  for (int d = 32; d > 0; d >>= 1) v = fmaxf(v, __shfl_xor(v, d, 64));
  if (l == 0) red[wv] = v;
  __syncthreads();
  if (t == 0) {
    float m = red[0];
    for (int k = 1; k < 8; ++k) m = fmaxf(m, red[k]);
    red[0] = m;
  }
  __syncthreads();
  float m = red[0];
  float e = (t == i) ? 0.f : expf(sc - m);
  float a = e;
  #pragma unroll
  for (int d = 32; d > 0; d >>= 1) a += __shfl_xor(a, d, 64);
  if (l == 0) red[8 + wv] = a;
  __syncthreads();
  if (t == 0) {
    float sm = 0.f;
    for (int k = 0; k < 8; ++k) sm += red[8 + k];
    red[8] = sm;
  }
  __syncthreads();
  A[(size_t)row * 512 + t] = e / red[8];
}

// ---------------- hp: out[b,i,t] = sum_j A * h ; f32 output both layers ----------------
template <int RELU>
__global__ __launch_bounds__(256) void k_hp(
    const float* __restrict__ A, const float* __restrict__ h, float* __restrict__ outf) {
  int blk = blockIdx.x;                // b*512 + i
  int b = blk >> 9, i = blk & 511;
  int t = threadIdx.x;                 // hd*64 + f
  int hd = t >> 6;
  const float* Arow = A + ((size_t)(b * 4 + hd) * 512 + i) * 512;
  const float* hb = h + (size_t)b * 512 * 256;
  float acc = 0.f;
  for (int j = 0; j < 512; ++j)
    acc = fmaf(Arow[j], hb[(size_t)j * 256 + t], acc);
  outf[(size_t)blk * 256 + t] = RELU ? fmaxf(acc, 0.f) : acc;
}

// ---------------- adjacency: analytic fill, f32 0/1, float4 stores ----------------
// Reads shot_type straight from the pristine input with a per-block i64/i32 sniff.
__global__ __launch_bounds__(256) void k_adjf(
    const unsigned* __restrict__ st_raw, float* __restrict__ adj) {
  __shared__ int i64_s;
  if (threadIdx.x == 0) {
    int hi0 = 0;
    for (int k = 0; k < 32; ++k) if (st_raw[2 * k + 1] == 0u) ++hi0;
    i64_s = (hi0 >= 30) ? 1 : 0;
  }
  __syncthreads();
  int is64 = i64_s;
  int chunk = blockIdx.x * 256 + threadIdx.x;   // float4 id
  int j0 = (chunk & 127) << 2;
  int rowid = chunk >> 7;
  int i = rowid & 511;
  int plane = rowid >> 9;                        // b*14 + r
  int r = plane % 14;
  int b = plane / 14;
  float vals[4];
  #pragma unroll
  for (int q = 0; q < 4; ++q) {
    int j = j0 + q;
    int d = j - i;
    int ad = d < 0 ? -d : d;
    int mn = d < 0 ? j : i;
    int m4 = mn & 3;
    float v = 0.f;
    if (r == 13) {
      bool excl = (d == 0) || (ad == 2) || (ad == 3 && m4 == 0) || (ad == 1 && m4 == 3);
      v = excl ? 0.f : 1.f;
    } else if (r == 11) {
      v = (ad == 2 && (m4 == 0 || m4 == 3)) ? 1.f : 0.f;
    } else if (r == 12) {
      v = (ad == 2 && (m4 == 1 || m4 == 2)) ? 1.f : 0.f;
    } else {
      bool sp = (ad == 3 && m4 == 0) || (ad == 1 && m4 == 3);
      if (sp) {
        int e = b * 255 + (mn >> 1);
        int stv = is64 ? (int)st_raw[2 * e] : (int)st_raw[e];
        v = (stv == r) ? 1.f : 0.f;
      }
    }
    vals[q] = v;
  }
  *(float4*)&adj[(size_t)chunk * 4] = make_float4(vals[0], vals[1], vals[2], vals[3]);
}

// ---------------- sentinel ----------------
__global__ void k_sentinel(float* out, float v) {
  if (threadIdx.x == 0 && blockIdx.x == 0) out[0] = v;
}

extern "C" void kernel_launch(void* const* d_in, const int* in_sizes, int n_in,
                              void* d_out, int out_size, void* d_ws, size_t ws_size,
                              hipStream_t stream) {
  static const int expA[16] = {64,8160,8192,8192,8192,8192,1,1120,64,32,4096,64,16384,512,65536,512};
  static const int expB[15] = {64,8160,8192,8192,8192,8192,1120,64,32,4096,64,16384,512,65536,512};
  int mismatch = -1;
  int base = 7;
  if (n_in == 16) {
    base = 7;
    for (int i = 0; i < 16; ++i) if (in_sizes[i] != expA[i]) { mismatch = i; break; }
  } else if (n_in == 15) {
    base = 6;
    for (int i = 0; i < 15; ++i) if (in_sizes[i] != expB[i]) { mismatch = i; break; }
  } else {
    mismatch = 17;
  }
  if (mismatch < 0 && out_size != NODE_ELEMS + ADJ_ELEMS) mismatch = 16;

  float* out_node = (float*)d_out;                 // f32 output model
  float* out_adjf = out_node + NODE_ELEMS;

  // Scratch carved from the f32 adj output region (470 MB); adj is written last.
  char* scr = (char*)out_adjf;
  float* x  = (float*)(scr);                       //  4 MB
  float* h  = (float*)(scr + (size_t)( 4u << 20)); // 16 MB
  float* x2 = (float*)(scr + (size_t)(24u << 20)); // 16 MB
  float* ss = (float*)(scr + (size_t)(44u << 20)); // 256 KB
  float* sd = (float*)(scr + (size_t)(45u << 20)); // 256 KB
  float* cv = (float*)(scr + (size_t)(48u << 20)); // converted inputs
  float* A  = (float*)(scr + (size_t)(64u << 20)); // attn matrix, 128 MB

  float* cAx  = cv + 0;
  float* cAy  = cv + 8192;
  float* cBx  = cv + 16384;
  float* cBy  = cv + 24576;
  float* cEmb = cv + 32768;
  float* cWc  = cv + 33888;
  float* cbc  = cv + 33952;
  float* cWm  = cv + 33984;
  float* cbm  = cv + 38080;
  float* cW1  = cv + 38144;
  float* cA1  = cv + 54528;
  float* cW2  = cv + 55040;
  float* cA2  = cv + 120576;
  int*   cPl  = (int*)(cv + 121088);

  ConvArgs a;
  a.src[0]  = d_in[2];        a.dst[0]  = cAx;  a.n[0]  = 8192;  a.kind[0]  = 0;
  a.src[1]  = d_in[3];        a.dst[1]  = cAy;  a.n[1]  = 8192;  a.kind[1]  = 0;
  a.src[2]  = d_in[4];        a.dst[2]  = cBx;  a.n[2]  = 8192;  a.kind[2]  = 0;
  a.src[3]  = d_in[5];        a.dst[3]  = cBy;  a.n[3]  = 8192;  a.kind[3]  = 0;
  a.src[4]  = d_in[base + 0]; a.dst[4]  = cEmb; a.n[4]  = 1120;  a.kind[4]  = 0;
  a.src[5]  = d_in[base + 1]; a.dst[5]  = cWc;  a.n[5]  = 64;    a.kind[5]  = 0;
  a.src[6]  = d_in[base + 2]; a.dst[6]  = cbc;  a.n[6]  = 32;    a.kind[6]  = 0;
  a.src[7]  = d_in[base + 3]; a.dst[7]  = cWm;  a.n[7]  = 4096;  a.kind[7]  = 0;
  a.src[8]  = d_in[base + 4]; a.dst[8]  = cbm;  a.n[8]  = 64;    a.kind[8]  = 0;
  a.src[9]  = d_in[base + 5]; a.dst[9]  = cW1;  a.n[9]  = 16384; a.kind[9]  = 0;
  a.src[10] = d_in[base + 6]; a.dst[10] = cA1;  a.n[10] = 512;   a.kind[10] = 0;
  a.src[11] = d_in[base + 7]; a.dst[11] = cW2;  a.n[11] = 65536; a.kind[11] = 0;
  a.src[12] = d_in[base + 8]; a.dst[12] = cA2;  a.n[12] = 512;   a.kind[12] = 0;
  a.src[13] = d_in[0];        a.dst[13] = cPl;  a.n[13] = 64;    a.kind[13] = 1;

  k_conv2<<<dim3(64, 14), 256, 0, stream>>>(a, (const unsigned*)d_in[base + 3],
                                            (const unsigned*)d_in[0]);

  k_feat2<<<BN / 256, 256, 0, stream>>>(cPl, cAx, cAy, cBx, cBy, cEmb, cWc, cbc, cWm, cbm, x);

  // ---- layer 1 ----
  k_gemm_naive<<<BN, 256, 0, stream>>>(x, cW1, h, 64);
  k_score<<<B_ * 4 * N_ / 256, 256, 0, stream>>>(h, cA1, ss, sd);
  k_attnrow<<<B_ * 4 * N_, 512, 0, stream>>>(ss, sd, A);
  k_hp<1><<<BN, 256, 0, stream>>>(A, h, x2);

  // ---- layer 2 ----
  k_gemm_naive<<<BN, 256, 0, stream>>>(x2, cW2, h, 256);
  k_score<<<B_ * 4 * N_ / 256, 256, 0, stream>>>(h, cA2, ss, sd);
  k_attnrow<<<B_ * 4 * N_, 512, 0, stream>>>(ss, sd, A);
  k_hp<0><<<BN, 256, 0, stream>>>(A, h, out_node);

  // ---- adjacency last (scratch lives in its output region) ----
  k_adjf<<<(ADJ_ELEMS / 4) / 256, 256, 0, stream>>>((const unsigned*)d_in[1], out_adjf);

  if (mismatch >= 0) {
    float v = ldexpf(1024.f, mismatch);
    k_sentinel<<<1, 64, 0, stream>>>(out_node, v);
  }
}

// Round 9
// 808.211 us; speedup vs baseline: 2.5964x; 2.5964x over previous
//
#include <hip/hip_runtime.h>
#include <hip/hip_bf16.h>
#include <stdint.h>

static constexpr int B_  = 32;
static constexpr int E_  = 256;
static constexpr int N_  = 512;    // 2E
static constexpr int C_  = 256;    // H*F
static constexpr int BN  = B_ * N_;
static constexpr int NODE_ELEMS = B_ * N_ * C_;          // 4,194,304
static constexpr int ADJ_ELEMS  = B_ * 14 * N_ * N_;     // 117,440,512

#define LOG2E 1.44269504088896340736f

// ---------------- dtype-agnostic input conversion ----------------
struct ConvArgs {
  const void* src[14];
  void* dst[14];
  int n[14];
  int kind[14];   // 0 = float array, 1 = int array
};

__global__ __launch_bounds__(256) void k_conv2(ConvArgs a, const unsigned* fprobe,
                                               const unsigned* iprobe) {
  __shared__ int fk_s, ik_s;
  int t = threadIdx.x;
  if (t == 0) {
    int c_even = 0, c_lo = 0;
    for (int k = 0; k < 32; ++k) {
      unsigned w = fprobe[2 * k];
      unsigned e32 = (w >> 23) & 0xFFu;
      unsigned elo = (w >> 7) & 0xFFu;
      if (e32 >= 105u && e32 <= 135u) ++c_even;
      if (elo >= 105u && elo <= 135u) ++c_lo;
    }
    fk_s = (c_even < 16) ? 2 : ((c_lo >= 16) ? 1 : 0);   // 2=f64, 1=bf16, 0=f32
    int hi0 = 0;
    for (int k = 0; k < 32; ++k) if (iprobe[2 * k + 1] == 0u) ++hi0;
    ik_s = (hi0 >= 30) ? 1 : 0;                          // 1=i64, 0=i32
  }
  __syncthreads();
  int fk = fk_s, ik = ik_s;
  int arr = blockIdx.y;
  int n = a.n[arr], kind = a.kind[arr];
  for (int idx = blockIdx.x * 256 + t; idx < n; idx += gridDim.x * 256) {
    if (kind == 0) {
      float v;
      if (fk == 2) {
        v = (float)((const double*)a.src[arr])[idx];
      } else if (fk == 1) {
        unsigned short u = ((const unsigned short*)a.src[arr])[idx];
        union { unsigned u; float f; } c; c.u = (unsigned)u << 16; v = c.f;
      } else {
        v = ((const float*)a.src[arr])[idx];
      }
      ((float*)a.dst[arr])[idx] = v;
    } else {
      int v;
      if (ik == 1) v = (int)((const long long*)a.src[arr])[idx];
      else         v = ((const int*)a.src[arr])[idx];
      ((int*)a.dst[arr])[idx] = v;
    }
  }
}

// ---------------- node features: one thread per node ----------------
__global__ __launch_bounds__(256) void k_feat2(
    const int* __restrict__ player, const float* __restrict__ Ax, const float* __restrict__ Ay,
    const float* __restrict__ Bx, const float* __restrict__ By,
    const float* __restrict__ emb, const float* __restrict__ Wc, const float* __restrict__ bc,
    const float* __restrict__ Wm, const float* __restrict__ bm, float* __restrict__ x) {
  int id = blockIdx.x * 256 + threadIdx.x;   // b*512 + n
  if (id >= BN) return;
  int b = id >> 9, n = id & 511;
  int e = n >> 1, side = n & 1;
  float cx = side ? Bx[b * E_ + e] : Ax[b * E_ + e];
  float cy = side ? By[b * E_ + e] : Ay[b * E_ + e];
  int pid = player[b * 2 + side];
  float ct[32];
  for (int k = 0; k < 32; ++k)
    ct[k] = fmaxf(fmaf(cx, Wc[k], fmaf(cy, Wc[32 + k], bc[k])), 0.f);
  for (int o = 0; o < 64; ++o) {
    float acc = bm[o];
    for (int c = 0; c < 32; ++c) acc = fmaf(ct[c], Wm[c * 64 + o], acc);
    for (int c = 0; c < 32; ++c) acc = fmaf(emb[pid * 32 + c], Wm[(32 + c) * 64 + o], acc);
    x[(size_t)id * 64 + o] = acc;
  }
}

// ---------------- tiled GEMM: h[BN,256] = x[BN,K] @ W[K,256] ----------------
__global__ __launch_bounds__(256) void k_gemm(
    const float* __restrict__ x, const float* __restrict__ W, float* __restrict__ h, int K) {
  __shared__ float xs[64 * 64];
  __shared__ float wt[64 * 64];
  int row0 = blockIdx.x * 64;
  int col0 = blockIdx.y * 64;
  int t = threadIdx.x;
  int tx = t & 15, ty = t >> 4;
  float acc[4][4] = {};
  for (int kt = 0; kt < K; kt += 64) {
    #pragma unroll
    for (int q = 0; q < 4; ++q) {
      int v = q * 256 + t;            // float4 chunk id 0..1023
      int r = v >> 4, c = (v & 15) * 4;
      *(float4*)&xs[r * 64 + c] = *(const float4*)&x[(size_t)(row0 + r) * K + kt + c];
      *(float4*)&wt[r * 64 + c] = *(const float4*)&W[(size_t)(kt + r) * C_ + col0 + c];
    }
    __syncthreads();
    #pragma unroll 4
    for (int k = 0; k < 64; ++k) {
      float xv[4];
      #pragma unroll
      for (int r = 0; r < 4; ++r) xv[r] = xs[(ty * 4 + r) * 64 + k];
      float4 wf = *(const float4*)&wt[k * 64 + tx * 4];
      #pragma unroll
      for (int r = 0; r < 4; ++r) {
        acc[r][0] = fmaf(xv[r], wf.x, acc[r][0]);
        acc[r][1] = fmaf(xv[r], wf.y, acc[r][1]);
        acc[r][2] = fmaf(xv[r], wf.z, acc[r][2]);
        acc[r][3] = fmaf(xv[r], wf.w, acc[r][3]);
      }
    }
    __syncthreads();
  }
  #pragma unroll
  for (int r = 0; r < 4; ++r) {
    int row = row0 + ty * 4 + r;
    float4 o = make_float4(acc[r][0], acc[r][1], acc[r][2], acc[r][3]);
    *(float4*)&h[(size_t)row * C_ + col0 + tx * 4] = o;
  }
}

// ---------------- s_src/s_dst: [B,H,N] ----------------
__global__ __launch_bounds__(256) void k_ssd(
    const float* __restrict__ h, const float* __restrict__ att,
    float* __restrict__ ss, float* __restrict__ sd) {
  int t = threadIdx.x;
  int wv = t >> 6, l = t & 63;
  int row = blockIdx.x * 4 + wv;       // b*512+n
  int b = row >> 9, n = row & 511;
  #pragma unroll
  for (int hd = 0; hd < 4; ++hd) {
    float v = h[(size_t)row * C_ + hd * 64 + l];
    float s1 = v * att[hd * 128 + l];
    float s2 = v * att[hd * 128 + 64 + l];
    #pragma unroll
    for (int d = 32; d > 0; d >>= 1) {
      s1 += __shfl_xor(s1, d, 64);
      s2 += __shfl_xor(s2, d, 64);
    }
    if (l == 0) {
      int idx = (b * 4 + hd) * N_ + n;
      ss[idx] = s1; sd[idx] = s2;
    }
  }
}

// ---------------- softmax stats: m2 = m*log2e, rl = 1/l ----------------
__global__ __launch_bounds__(256) void k_ml(
    const float* __restrict__ ss, const float* __restrict__ sd,
    float* __restrict__ m2, float* __restrict__ rl) {
  int t = threadIdx.x;
  int wv = t >> 6, l = t & 63;
  int row = blockIdx.x * 4 + wv;       // bh*512 + i
  int bh = row >> 9, i = row & 511;
  const float* sdb = sd + (size_t)bh * N_;
  float mx = -1e30f;
  #pragma unroll
  for (int q = 0; q < 8; ++q) mx = fmaxf(mx, sdb[q * 64 + l]);
  #pragma unroll
  for (int d = 32; d > 0; d >>= 1) mx = fmaxf(mx, __shfl_xor(mx, d, 64));
  float ssi = ss[row];
  float s = ssi + mx;
  float mm2 = fmaxf(s, 0.2f * s) * LOG2E;   // leaky monotone -> row-max bound
  float acc = 0.f;
  #pragma unroll
  for (int q = 0; q < 8; ++q) {
    int j = q * 64 + l;
    float sc = ssi + sdb[j];
    sc = fmaxf(sc, 0.2f * sc);
    float e = exp2f(fmaf(sc, LOG2E, -mm2));
    acc += (j == i) ? 0.f : e;
  }
  #pragma unroll
  for (int d = 32; d > 0; d >>= 1) acc += __shfl_xor(acc, d, 64);
  if (l == 0) { m2[row] = mm2; rl[row] = 1.f / acc; }
}

// ---------------- fused attention: out[b,i,hd*64+f] = (P @ h_slice) * rl ----------------
template <int RELU>
__global__ __launch_bounds__(256) void k_attn(
    const float* __restrict__ h, const float* __restrict__ ss, const float* __restrict__ sd,
    const float* __restrict__ m2, const float* __restrict__ rl, float* __restrict__ outf) {
  __shared__ float hs[64 * 64];        // [j][f]
  __shared__ float Pt[64 * 132];       // [j][i] padded
  __shared__ float sdl[64];
  int blk = blockIdx.x;
  int it = blk & 3, hd = (blk >> 2) & 3, b = blk >> 4;
  int i0 = it * 128;
  int bh = b * 4 + hd;
  int t = threadIdx.x;
  int w = t >> 6, l = t & 63;
  int ib  = (w & 1) * 64 + l;          // build-phase i (0..127)
  int jb0 = (w >> 1) * 32;             // build-phase j range
  float ssb = ss[(size_t)bh * N_ + i0 + ib];
  float m2b = m2[(size_t)bh * N_ + i0 + ib];
  int tx = t & 15, ty = t >> 4;
  int f0 = tx * 4, im0 = ty * 8;
  float acc[8][4] = {};
  for (int jt = 0; jt < 8; ++jt) {
    int j0 = jt * 64;
    #pragma unroll
    for (int q = 0; q < 4; ++q) {
      int v = q * 256 + t;            // float4 chunk id 0..1023
      int r = v >> 4, c = (v & 15) * 4;
      *(float4*)&hs[r * 64 + c] =
          *(const float4*)&h[(size_t)(b * N_ + j0 + r) * C_ + hd * 64 + c];
    }
    if (t < 64) sdl[t] = sd[(size_t)bh * N_ + j0 + t];
    __syncthreads();
    #pragma unroll 8
    for (int jj = 0; jj < 32; ++jj) {
      int j = jb0 + jj;
      float s = ssb + sdl[j];
      float sc = fmaxf(s, 0.2f * s);
      float p = exp2f(fmaf(sc, LOG2E, -m2b));
      if (i0 + ib == j0 + j) p = 0.f;
      Pt[j * 132 + ib] = p;
    }
    __syncthreads();
    for (int j = 0; j < 64; ++j) {
      float4 hv = *(const float4*)&hs[j * 64 + f0];
      float4 p0 = *(const float4*)&Pt[j * 132 + im0];
      float4 p1 = *(const float4*)&Pt[j * 132 + im0 + 4];
      float pr[8] = {p0.x,p0.y,p0.z,p0.w,p1.x,p1.y,p1.z,p1.w};
      #pragma unroll
      for (int r = 0; r < 8; ++r) {
        acc[r][0] = fmaf(pr[r], hv.x, acc[r][0]);
        acc[r][1] = fmaf(pr[r], hv.y, acc[r][1]);
        acc[r][2] = fmaf(pr[r], hv.z, acc[r][2]);
        acc[r][3] = fmaf(pr[r], hv.w, acc[r][3]);
      }
    }
    __syncthreads();
  }
  #pragma unroll
  for (int r = 0; r < 8; ++r) {
    int i = i0 + im0 + r;
    float scale = rl[(size_t)bh * N_ + i];
    size_t o = (size_t)(b * N_ + i) * C_ + hd * 64 + f0;
    float4 v = make_float4(acc[r][0]*scale, acc[r][1]*scale, acc[r][2]*scale, acc[r][3]*scale);
    if constexpr (RELU) {
      v.x = fmaxf(v.x, 0.f); v.y = fmaxf(v.y, 0.f);
      v.z = fmaxf(v.z, 0.f); v.w = fmaxf(v.w, 0.f);
    }
    *(float4*)&outf[o] = v;
  }
}

// ---------------- adjacency: analytic fill, f32 0/1, float4 stores ----------------
__global__ __launch_bounds__(256) void k_adjf(
    const unsigned* __restrict__ st_raw, float* __restrict__ adj) {
  __shared__ int i64_s;
  if (threadIdx.x == 0) {
    int hi0 = 0;
    for (int k = 0; k < 32; ++k) if (st_raw[2 * k + 1] == 0u) ++hi0;
    i64_s = (hi0 >= 30) ? 1 : 0;
  }
  __syncthreads();
  int is64 = i64_s;
  int chunk = blockIdx.x * 256 + threadIdx.x;   // float4 id
  int j0 = (chunk & 127) << 2;
  int rowid = chunk >> 7;
  int i = rowid & 511;
  int plane = rowid >> 9;                        // b*14 + r
  int r = plane % 14;
  int b = plane / 14;
  float vals[4];
  #pragma unroll
  for (int q = 0; q < 4; ++q) {
    int j = j0 + q;
    int d = j - i;
    int ad = d < 0 ? -d : d;
    int mn = d < 0 ? j : i;
    int m4 = mn & 3;
    float v = 0.f;
    if (r == 13) {
      bool excl = (d == 0) || (ad == 2) || (ad == 3 && m4 == 0) || (ad == 1 && m4 == 3);
      v = excl ? 0.f : 1.f;
    } else if (r == 11) {
      v = (ad == 2 && (m4 == 0 || m4 == 3)) ? 1.f : 0.f;
    } else if (r == 12) {
      v = (ad == 2 && (m4 == 1 || m4 == 2)) ? 1.f : 0.f;
    } else {
      bool sp = (ad == 3 && m4 == 0) || (ad == 1 && m4 == 3);
      if (sp) {
        int e = b * 255 + (mn >> 1);
        int stv = is64 ? (int)st_raw[2 * e] : (int)st_raw[e];
        v = (stv == r) ? 1.f : 0.f;
      }
    }
    vals[q] = v;
  }
  *(float4*)&adj[(size_t)chunk * 4] = make_float4(vals[0], vals[1], vals[2], vals[3]);
}

// ---------------- sentinel ----------------
__global__ void k_sentinel(float* out, float v) {
  if (threadIdx.x == 0 && blockIdx.x == 0) out[0] = v;
}

extern "C" void kernel_launch(void* const* d_in, const int* in_sizes, int n_in,
                              void* d_out, int out_size, void* d_ws, size_t ws_size,
                              hipStream_t stream) {
  static const int expA[16] = {64,8160,8192,8192,8192,8192,1,1120,64,32,4096,64,16384,512,65536,512};
  static const int expB[15] = {64,8160,8192,8192,8192,8192,1120,64,32,4096,64,16384,512,65536,512};
  int mismatch = -1;
  int base = 7;
  if (n_in == 16) {
    base = 7;
    for (int i = 0; i < 16; ++i) if (in_sizes[i] != expA[i]) { mismatch = i; break; }
  } else if (n_in == 15) {
    base = 6;
    for (int i = 0; i < 15; ++i) if (in_sizes[i] != expB[i]) { mismatch = i; break; }
  } else {
    mismatch = 17;
  }
  if (mismatch < 0 && out_size != NODE_ELEMS + ADJ_ELEMS) mismatch = 16;

  float* out_node = (float*)d_out;                 // f32 output
  float* out_adjf = out_node + NODE_ELEMS;

  // Scratch carved from the f32 adj output region (470 MB); adj written last.
  char* scr = (char*)out_adjf;
  float* x  = (float*)(scr);                       //  4 MB
  float* h  = (float*)(scr + (size_t)( 4u << 20)); // 16 MB
  float* x2 = (float*)(scr + (size_t)(24u << 20)); // 16 MB
  float* ss = (float*)(scr + (size_t)(44u << 20)); // 256 KB
  float* sd = (float*)(scr + (size_t)(45u << 20)); // 256 KB
  float* m2 = (float*)(scr + (size_t)(46u << 20)); // 256 KB
  float* rl = (float*)(scr + (size_t)(47u << 20)); // 256 KB
  float* cv = (float*)(scr + (size_t)(48u << 20)); // converted inputs

  float* cAx  = cv + 0;
  float* cAy  = cv + 8192;
  float* cBx  = cv + 16384;
  float* cBy  = cv + 24576;
  float* cEmb = cv + 32768;
  float* cWc  = cv + 33888;
  float* cbc  = cv + 33952;
  float* cWm  = cv + 33984;
  float* cbm  = cv + 38080;
  float* cW1  = cv + 38144;
  float* cA1  = cv + 54528;
  float* cW2  = cv + 55040;
  float* cA2  = cv + 120576;
  int*   cPl  = (int*)(cv + 121088);

  ConvArgs a;
  a.src[0]  = d_in[2];        a.dst[0]  = cAx;  a.n[0]  = 8192;  a.kind[0]  = 0;
  a.src[1]  = d_in[3];        a.dst[1]  = cAy;  a.n[1]  = 8192;  a.kind[1]  = 0;
  a.src[2]  = d_in[4];        a.dst[2]  = cBx;  a.n[2]  = 8192;  a.kind[2]  = 0;
  a.src[3]  = d_in[5];        a.dst[3]  = cBy;  a.n[3]  = 8192;  a.kind[3]  = 0;
  a.src[4]  = d_in[base + 0]; a.dst[4]  = cEmb; a.n[4]  = 1120;  a.kind[4]  = 0;
  a.src[5]  = d_in[base + 1]; a.dst[5]  = cWc;  a.n[5]  = 64;    a.kind[5]  = 0;
  a.src[6]  = d_in[base + 2]; a.dst[6]  = cbc;  a.n[6]  = 32;    a.kind[6]  = 0;
  a.src[7]  = d_in[base + 3]; a.dst[7]  = cWm;  a.n[7]  = 4096;  a.kind[7]  = 0;
  a.src[8]  = d_in[base + 4]; a.dst[8]  = cbm;  a.n[8]  = 64;    a.kind[8]  = 0;
  a.src[9]  = d_in[base + 5]; a.dst[9]  = cW1;  a.n[9]  = 16384; a.kind[9]  = 0;
  a.src[10] = d_in[base + 6]; a.dst[10] = cA1;  a.n[10] = 512;   a.kind[10] = 0;
  a.src[11] = d_in[base + 7]; a.dst[11] = cW2;  a.n[11] = 65536; a.kind[11] = 0;
  a.src[12] = d_in[base + 8]; a.dst[12] = cA2;  a.n[12] = 512;   a.kind[12] = 0;
  a.src[13] = d_in[0];        a.dst[13] = cPl;  a.n[13] = 64;    a.kind[13] = 1;

  k_conv2<<<dim3(64, 14), 256, 0, stream>>>(a, (const unsigned*)d_in[base + 3],
                                            (const unsigned*)d_in[0]);

  k_feat2<<<BN / 256, 256, 0, stream>>>(cPl, cAx, cAy, cBx, cBy, cEmb, cWc, cbc, cWm, cbm, x);

  // ---- layer 1 ----
  k_gemm<<<dim3(BN / 64, 4), 256, 0, stream>>>(x, cW1, h, 64);
  k_ssd<<<BN / 4, 256, 0, stream>>>(h, cA1, ss, sd);
  k_ml<<<B_ * 4 * N_ / 4, 256, 0, stream>>>(ss, sd, m2, rl);
  k_attn<1><<<B_ * 4 * (N_ / 128), 256, 0, stream>>>(h, ss, sd, m2, rl, x2);

  // ---- layer 2 ----
  k_gemm<<<dim3(BN / 64, 4), 256, 0, stream>>>(x2, cW2, h, 256);
  k_ssd<<<BN / 4, 256, 0, stream>>>(h, cA2, ss, sd);
  k_ml<<<B_ * 4 * N_ / 4, 256, 0, stream>>>(ss, sd, m2, rl);
  k_attn<0><<<B_ * 4 * (N_ / 128), 256, 0, stream>>>(h, ss, sd, m2, rl, out_node);

  // ---- adjacency last (scratch lives in its output region) ----
  k_adjf<<<(ADJ_ELEMS / 4) / 256, 256, 0, stream>>>((const unsigned*)d_in[1], out_adjf);

  if (mismatch >= 0) {
    float v = ldexpf(1024.f, mismatch);
    k_sentinel<<<1, 64, 0, stream>>>(out_node, v);
  }
}

// Round 10
// 781.219 us; speedup vs baseline: 2.6861x; 1.0346x over previous
//
#include <hip/hip_runtime.h>
#include <hip/hip_bf16.h>
#include <stdint.h>

static constexpr int B_  = 32;
static constexpr int E_  = 256;
static constexpr int N_  = 512;    // 2E
static constexpr int C_  = 256;    // H*F
static constexpr int BN  = B_ * N_;
static constexpr int NODE_ELEMS = B_ * N_ * C_;          // 4,194,304
static constexpr int ADJ_ELEMS  = B_ * 14 * N_ * N_;     // 117,440,512

#define LOG2E 1.44269504088896340736f

// ---------------- dtype-agnostic input conversion ----------------
struct ConvArgs {
  const void* src[15];
  void* dst[15];
  int n[15];
  int kind[15];   // 0 = float array, 1 = int array
};

__global__ __launch_bounds__(256) void k_conv2(ConvArgs a, const unsigned* fprobe,
                                               const unsigned* iprobe) {
  __shared__ int fk_s, ik_s;
  int t = threadIdx.x;
  if (t == 0) {
    int c_even = 0, c_lo = 0;
    for (int k = 0; k < 32; ++k) {
      unsigned w = fprobe[2 * k];
      unsigned e32 = (w >> 23) & 0xFFu;
      unsigned elo = (w >> 7) & 0xFFu;
      if (e32 >= 105u && e32 <= 135u) ++c_even;
      if (elo >= 105u && elo <= 135u) ++c_lo;
    }
    fk_s = (c_even < 16) ? 2 : ((c_lo >= 16) ? 1 : 0);   // 2=f64, 1=bf16, 0=f32
    int hi0 = 0;
    for (int k = 0; k < 32; ++k) if (iprobe[2 * k + 1] == 0u) ++hi0;
    ik_s = (hi0 >= 30) ? 1 : 0;                          // 1=i64, 0=i32
  }
  __syncthreads();
  int fk = fk_s, ik = ik_s;
  int arr = blockIdx.y;
  int n = a.n[arr], kind = a.kind[arr];
  for (int idx = blockIdx.x * 256 + t; idx < n; idx += gridDim.x * 256) {
    if (kind == 0) {
      float v;
      if (fk == 2) {
        v = (float)((const double*)a.src[arr])[idx];
      } else if (fk == 1) {
        unsigned short u = ((const unsigned short*)a.src[arr])[idx];
        union { unsigned u; float f; } c; c.u = (unsigned)u << 16; v = c.f;
      } else {
        v = ((const float*)a.src[arr])[idx];
      }
      ((float*)a.dst[arr])[idx] = v;
    } else {
      int v;
      if (ik == 1) v = (int)((const long long*)a.src[arr])[idx];
      else         v = ((const int*)a.src[arr])[idx];
      ((int*)a.dst[arr])[idx] = v;
    }
  }
}

// ---------------- node features: one thread per node, 64-thr blocks ----------------
__global__ __launch_bounds__(64) void k_feat2(
    const int* __restrict__ player, const float* __restrict__ Ax, const float* __restrict__ Ay,
    const float* __restrict__ Bx, const float* __restrict__ By,
    const float* __restrict__ emb, const float* __restrict__ Wc, const float* __restrict__ bc,
    const float* __restrict__ Wm, const float* __restrict__ bm, float* __restrict__ x) {
  int id = blockIdx.x * 64 + threadIdx.x;   // b*512 + n
  if (id >= BN) return;
  int b = id >> 9, n = id & 511;
  int e = n >> 1, side = n & 1;
  float cx = side ? Bx[b * E_ + e] : Ax[b * E_ + e];
  float cy = side ? By[b * E_ + e] : Ay[b * E_ + e];
  int pid = player[b * 2 + side];
  float ct[32];
  for (int k = 0; k < 32; ++k)
    ct[k] = fmaxf(fmaf(cx, Wc[k], fmaf(cy, Wc[32 + k], bc[k])), 0.f);
  for (int o = 0; o < 64; ++o) {
    float acc = bm[o];
    for (int c = 0; c < 32; ++c) acc = fmaf(ct[c], Wm[c * 64 + o], acc);
    for (int c = 0; c < 32; ++c) acc = fmaf(emb[pid * 32 + c], Wm[(32 + c) * 64 + o], acc);
    x[(size_t)id * 64 + o] = acc;
  }
}

// ---------------- tiled GEMM: h[BN,256] = x[BN,K] @ W[K,256] ----------------
__global__ __launch_bounds__(256) void k_gemm(
    const float* __restrict__ x, const float* __restrict__ W, float* __restrict__ h, int K) {
  __shared__ float xs[64 * 64];
  __shared__ float wt[64 * 64];
  int row0 = blockIdx.x * 64;
  int col0 = blockIdx.y * 64;
  int t = threadIdx.x;
  int tx = t & 15, ty = t >> 4;
  float acc[4][4] = {};
  for (int kt = 0; kt < K; kt += 64) {
    #pragma unroll
    for (int q = 0; q < 4; ++q) {
      int v = q * 256 + t;            // float4 chunk id 0..1023
      int r = v >> 4, c = (v & 15) * 4;
      *(float4*)&xs[r * 64 + c] = *(const float4*)&x[(size_t)(row0 + r) * K + kt + c];
      *(float4*)&wt[r * 64 + c] = *(const float4*)&W[(size_t)(kt + r) * C_ + col0 + c];
    }
    __syncthreads();
    #pragma unroll 4
    for (int k = 0; k < 64; ++k) {
      float xv[4];
      #pragma unroll
      for (int r = 0; r < 4; ++r) xv[r] = xs[(ty * 4 + r) * 64 + k];
      float4 wf = *(const float4*)&wt[k * 64 + tx * 4];
      #pragma unroll
      for (int r = 0; r < 4; ++r) {
        acc[r][0] = fmaf(xv[r], wf.x, acc[r][0]);
        acc[r][1] = fmaf(xv[r], wf.y, acc[r][1]);
        acc[r][2] = fmaf(xv[r], wf.z, acc[r][2]);
        acc[r][3] = fmaf(xv[r], wf.w, acc[r][3]);
      }
    }
    __syncthreads();
  }
  #pragma unroll
  for (int r = 0; r < 4; ++r) {
    int row = row0 + ty * 4 + r;
    float4 o = make_float4(acc[r][0], acc[r][1], acc[r][2], acc[r][3]);
    *(float4*)&h[(size_t)row * C_ + col0 + tx * 4] = o;
  }
}

// ---------------- s_src/s_dst: [B,H,N] ----------------
__global__ __launch_bounds__(256) void k_ssd(
    const float* __restrict__ h, const float* __restrict__ att,
    float* __restrict__ ss, float* __restrict__ sd) {
  int t = threadIdx.x;
  int wv = t >> 6, l = t & 63;
  int row = blockIdx.x * 4 + wv;       // b*512+n
  int b = row >> 9, n = row & 511;
  #pragma unroll
  for (int hd = 0; hd < 4; ++hd) {
    float v = h[(size_t)row * C_ + hd * 64 + l];
    float s1 = v * att[hd * 128 + l];
    float s2 = v * att[hd * 128 + 64 + l];
    #pragma unroll
    for (int d = 32; d > 0; d >>= 1) {
      s1 += __shfl_xor(s1, d, 64);
      s2 += __shfl_xor(s2, d, 64);
    }
    if (l == 0) {
      int idx = (b * 4 + hd) * N_ + n;
      ss[idx] = s1; sd[idx] = s2;
    }
  }
}

// ---------------- softmax stats: m2 = m*log2e, rl = 1/l ----------------
__global__ __launch_bounds__(256) void k_ml(
    const float* __restrict__ ss, const float* __restrict__ sd,
    float* __restrict__ m2, float* __restrict__ rl) {
  int t = threadIdx.x;
  int wv = t >> 6, l = t & 63;
  int row = blockIdx.x * 4 + wv;       // bh*512 + i
  int bh = row >> 9, i = row & 511;
  const float* sdb = sd + (size_t)bh * N_;
  float mx = -1e30f;
  #pragma unroll
  for (int q = 0; q < 8; ++q) mx = fmaxf(mx, sdb[q * 64 + l]);
  #pragma unroll
  for (int d = 32; d > 0; d >>= 1) mx = fmaxf(mx, __shfl_xor(mx, d, 64));
  float ssi = ss[row];
  float s = ssi + mx;
  float mm2 = fmaxf(s, 0.2f * s) * LOG2E;   // leaky monotone -> row-max bound
  float acc = 0.f;
  #pragma unroll
  for (int q = 0; q < 8; ++q) {
    int j = q * 64 + l;
    float sc = ssi + sdb[j];
    sc = fmaxf(sc, 0.2f * sc);
    float e = exp2f(fmaf(sc, LOG2E, -mm2));
    acc += (j == i) ? 0.f : e;
  }
  #pragma unroll
  for (int d = 32; d > 0; d >>= 1) acc += __shfl_xor(acc, d, 64);
  if (l == 0) { m2[row] = mm2; rl[row] = 1.f / acc; }
}

// ---------------- fused attention: out[b,i,hd*64+f] = (P @ h_slice) * rl ----------------
template <int RELU>
__global__ __launch_bounds__(256) void k_attn(
    const float* __restrict__ h, const float* __restrict__ ss, const float* __restrict__ sd,
    const float* __restrict__ m2, const float* __restrict__ rl, float* __restrict__ outf) {
  __shared__ float hs[64 * 64];        // [j][f]
  __shared__ float Pt[64 * 132];       // [j][i] padded
  __shared__ float sdl[64];
  int blk = blockIdx.x;
  int it = blk & 3, hd = (blk >> 2) & 3, b = blk >> 4;
  int i0 = it * 128;
  int bh = b * 4 + hd;
  int t = threadIdx.x;
  int w = t >> 6, l = t & 63;
  int ib  = (w & 1) * 64 + l;          // build-phase i (0..127)
  int jb0 = (w >> 1) * 32;             // build-phase j range
  float ssb = ss[(size_t)bh * N_ + i0 + ib];
  float m2b = m2[(size_t)bh * N_ + i0 + ib];
  int tx = t & 15, ty = t >> 4;
  int f0 = tx * 4, im0 = ty * 8;
  float acc[8][4] = {};
  for (int jt = 0; jt < 8; ++jt) {
    int j0 = jt * 64;
    #pragma unroll
    for (int q = 0; q < 4; ++q) {
      int v = q * 256 + t;            // float4 chunk id 0..1023
      int r = v >> 4, c = (v & 15) * 4;
      *(float4*)&hs[r * 64 + c] =
          *(const float4*)&h[(size_t)(b * N_ + j0 + r) * C_ + hd * 64 + c];
    }
    if (t < 64) sdl[t] = sd[(size_t)bh * N_ + j0 + t];
    __syncthreads();
    #pragma unroll 8
    for (int jj = 0; jj < 32; ++jj) {
      int j = jb0 + jj;
      float s = ssb + sdl[j];
      float sc = fmaxf(s, 0.2f * s);
      float p = exp2f(fmaf(sc, LOG2E, -m2b));
      if (i0 + ib == j0 + j) p = 0.f;
      Pt[j * 132 + ib] = p;
    }
    __syncthreads();
    for (int j = 0; j < 64; ++j) {
      float4 hv = *(const float4*)&hs[j * 64 + f0];
      float4 p0 = *(const float4*)&Pt[j * 132 + im0];
      float4 p1 = *(const float4*)&Pt[j * 132 + im0 + 4];
      float pr[8] = {p0.x,p0.y,p0.z,p0.w,p1.x,p1.y,p1.z,p1.w};
      #pragma unroll
      for (int r = 0; r < 8; ++r) {
        acc[r][0] = fmaf(pr[r], hv.x, acc[r][0]);
        acc[r][1] = fmaf(pr[r], hv.y, acc[r][1]);
        acc[r][2] = fmaf(pr[r], hv.z, acc[r][2]);
        acc[r][3] = fmaf(pr[r], hv.w, acc[r][3]);
      }
    }
    __syncthreads();
  }
  #pragma unroll
  for (int r = 0; r < 8; ++r) {
    int i = i0 + im0 + r;
    float scale = rl[(size_t)bh * N_ + i];
    size_t o = (size_t)(b * N_ + i) * C_ + hd * 64 + f0;
    float4 v = make_float4(acc[r][0]*scale, acc[r][1]*scale, acc[r][2]*scale, acc[r][3]*scale);
    if constexpr (RELU) {
      v.x = fmaxf(v.x, 0.f); v.y = fmaxf(v.y, 0.f);
      v.z = fmaxf(v.z, 0.f); v.w = fmaxf(v.w, 0.f);
    }
    *(float4*)&outf[o] = v;
  }
}

// ---------------- adjacency v2: pure analytic fill from converted i32 st ----------------
__global__ __launch_bounds__(256) void k_adjf2(
    const int* __restrict__ st, float* __restrict__ adj) {
  int chunk = blockIdx.x * 256 + threadIdx.x;   // float4 id
  int j0 = (chunk & 127) << 2;
  int rowid = chunk >> 7;
  int i = rowid & 511;
  int plane = rowid >> 9;                        // b*14 + r
  int r = plane % 14;
  int b = plane / 14;
  float vals[4];
  #pragma unroll
  for (int q = 0; q < 4; ++q) {
    int j = j0 + q;
    int d = j - i;
    int ad = d < 0 ? -d : d;
    int mn = d < 0 ? j : i;
    int m4 = mn & 3;
    float v = 0.f;
    if (r == 13) {
      bool excl = (d == 0) || (ad == 2) || (ad == 3 && m4 == 0) || (ad == 1 && m4 == 3);
      v = excl ? 0.f : 1.f;
    } else if (r == 11) {
      v = (ad == 2 && (m4 == 0 || m4 == 3)) ? 1.f : 0.f;
    } else if (r == 12) {
      v = (ad == 2 && (m4 == 1 || m4 == 2)) ? 1.f : 0.f;
    } else {
      bool sp = (ad == 3 && m4 == 0) || (ad == 1 && m4 == 3);
      if (sp) v = (st[b * 255 + (mn >> 1)] == r) ? 1.f : 0.f;
    }
    vals[q] = v;
  }
  *(float4*)&adj[(size_t)chunk * 4] = make_float4(vals[0], vals[1], vals[2], vals[3]);
}

// ---------------- adjacency fallback: raw input + per-block sniff (ws too small) ----------------
__global__ __launch_bounds__(256) void k_adjf(
    const unsigned* __restrict__ st_raw, float* __restrict__ adj) {
  __shared__ int i64_s;
  if (threadIdx.x == 0) {
    int hi0 = 0;
    for (int k = 0; k < 32; ++k) if (st_raw[2 * k + 1] == 0u) ++hi0;
    i64_s = (hi0 >= 30) ? 1 : 0;
  }
  __syncthreads();
  int is64 = i64_s;
  int chunk = blockIdx.x * 256 + threadIdx.x;
  int j0 = (chunk & 127) << 2;
  int rowid = chunk >> 7;
  int i = rowid & 511;
  int plane = rowid >> 9;
  int r = plane % 14;
  int b = plane / 14;
  float vals[4];
  #pragma unroll
  for (int q = 0; q < 4; ++q) {
    int j = j0 + q;
    int d = j - i;
    int ad = d < 0 ? -d : d;
    int mn = d < 0 ? j : i;
    int m4 = mn & 3;
    float v = 0.f;
    if (r == 13) {
      bool excl = (d == 0) || (ad == 2) || (ad == 3 && m4 == 0) || (ad == 1 && m4 == 3);
      v = excl ? 0.f : 1.f;
    } else if (r == 11) {
      v = (ad == 2 && (m4 == 0 || m4 == 3)) ? 1.f : 0.f;
    } else if (r == 12) {
      v = (ad == 2 && (m4 == 1 || m4 == 2)) ? 1.f : 0.f;
    } else {
      bool sp = (ad == 3 && m4 == 0) || (ad == 1 && m4 == 3);
      if (sp) {
        int e = b * 255 + (mn >> 1);
        int stv = is64 ? (int)st_raw[2 * e] : (int)st_raw[e];
        v = (stv == r) ? 1.f : 0.f;
      }
    }
    vals[q] = v;
  }
  *(float4*)&adj[(size_t)chunk * 4] = make_float4(vals[0], vals[1], vals[2], vals[3]);
}

// ---------------- sentinel ----------------
__global__ void k_sentinel(float* out, float v) {
  if (threadIdx.x == 0 && blockIdx.x == 0) out[0] = v;
}

extern "C" void kernel_launch(void* const* d_in, const int* in_sizes, int n_in,
                              void* d_out, int out_size, void* d_ws, size_t ws_size,
                              hipStream_t stream) {
  static const int expA[16] = {64,8160,8192,8192,8192,8192,1,1120,64,32,4096,64,16384,512,65536,512};
  static const int expB[15] = {64,8160,8192,8192,8192,8192,1120,64,32,4096,64,16384,512,65536,512};
  int mismatch = -1;
  int base = 7;
  if (n_in == 16) {
    base = 7;
    for (int i = 0; i < 16; ++i) if (in_sizes[i] != expA[i]) { mismatch = i; break; }
  } else if (n_in == 15) {
    base = 6;
    for (int i = 0; i < 15; ++i) if (in_sizes[i] != expB[i]) { mismatch = i; break; }
  } else {
    mismatch = 17;
  }
  if (mismatch < 0 && out_size != NODE_ELEMS + ADJ_ELEMS) mismatch = 16;

  float* out_node = (float*)d_out;                 // f32 output
  float* out_adjf = out_node + NODE_ELEMS;

  // Scratch carved from the f32 adj output region (470 MB); adj written last.
  char* scr = (char*)out_adjf;
  float* x  = (float*)(scr);                       //  4 MB
  float* h  = (float*)(scr + (size_t)( 4u << 20)); // 16 MB
  float* x2 = (float*)(scr + (size_t)(24u << 20)); // 16 MB
  float* ss = (float*)(scr + (size_t)(44u << 20)); // 256 KB
  float* sd = (float*)(scr + (size_t)(45u << 20)); // 256 KB
  float* m2 = (float*)(scr + (size_t)(46u << 20)); // 256 KB
  float* rl = (float*)(scr + (size_t)(47u << 20)); // 256 KB
  float* cv = (float*)(scr + (size_t)(48u << 20)); // converted inputs

  float* cAx  = cv + 0;
  float* cAy  = cv + 8192;
  float* cBx  = cv + 16384;
  float* cBy  = cv + 24576;
  float* cEmb = cv + 32768;
  float* cWc  = cv + 33888;
  float* cbc  = cv + 33952;
  float* cWm  = cv + 33984;
  float* cbm  = cv + 38080;
  float* cW1  = cv + 38144;
  float* cA1  = cv + 54528;
  float* cW2  = cv + 55040;
  float* cA2  = cv + 120576;
  int*   cPl  = (int*)(cv + 121088);

  // Converted shot_type goes to d_ws (survives until k_adjf2, outside adj region).
  bool ws_ok = (ws_size >= 8160 * sizeof(int));
  int* cSt = ws_ok ? (int*)d_ws : nullptr;

  ConvArgs a;
  a.src[0]  = d_in[2];        a.dst[0]  = cAx;  a.n[0]  = 8192;  a.kind[0]  = 0;
  a.src[1]  = d_in[3];        a.dst[1]  = cAy;  a.n[1]  = 8192;  a.kind[1]  = 0;
  a.src[2]  = d_in[4];        a.dst[2]  = cBx;  a.n[2]  = 8192;  a.kind[2]  = 0;
  a.src[3]  = d_in[5];        a.dst[3]  = cBy;  a.n[3]  = 8192;  a.kind[3]  = 0;
  a.src[4]  = d_in[base + 0]; a.dst[4]  = cEmb; a.n[4]  = 1120;  a.kind[4]  = 0;
  a.src[5]  = d_in[base + 1]; a.dst[5]  = cWc;  a.n[5]  = 64;    a.kind[5]  = 0;
  a.src[6]  = d_in[base + 2]; a.dst[6]  = cbc;  a.n[6]  = 32;    a.kind[6]  = 0;
  a.src[7]  = d_in[base + 3]; a.dst[7]  = cWm;  a.n[7]  = 4096;  a.kind[7]  = 0;
  a.src[8]  = d_in[base + 4]; a.dst[8]  = cbm;  a.n[8]  = 64;    a.kind[8]  = 0;
  a.src[9]  = d_in[base + 5]; a.dst[9]  = cW1;  a.n[9]  = 16384; a.kind[9]  = 0;
  a.src[10] = d_in[base + 6]; a.dst[10] = cA1;  a.n[10] = 512;   a.kind[10] = 0;
  a.src[11] = d_in[base + 7]; a.dst[11] = cW2;  a.n[11] = 65536; a.kind[11] = 0;
  a.src[12] = d_in[base + 8]; a.dst[12] = cA2;  a.n[12] = 512;   a.kind[12] = 0;
  a.src[13] = d_in[0];        a.dst[13] = cPl;  a.n[13] = 64;    a.kind[13] = 1;
  a.src[14] = d_in[1];        a.dst[14] = ws_ok ? (void*)cSt : (void*)cPl;
  a.n[14] = ws_ok ? 8160 : 0; a.kind[14] = 1;

  k_conv2<<<dim3(64, 15), 256, 0, stream>>>(a, (const unsigned*)d_in[base + 3],
                                            (const unsigned*)d_in[0]);

  k_feat2<<<BN / 64, 64, 0, stream>>>(cPl, cAx, cAy, cBx, cBy, cEmb, cWc, cbc, cWm, cbm, x);

  // ---- layer 1 ----
  k_gemm<<<dim3(BN / 64, 4), 256, 0, stream>>>(x, cW1, h, 64);
  k_ssd<<<BN / 4, 256, 0, stream>>>(h, cA1, ss, sd);
  k_ml<<<B_ * 4 * N_ / 4, 256, 0, stream>>>(ss, sd, m2, rl);
  k_attn<1><<<B_ * 4 * (N_ / 128), 256, 0, stream>>>(h, ss, sd, m2, rl, x2);

  // ---- layer 2 ----
  k_gemm<<<dim3(BN / 64, 4), 256, 0, stream>>>(x2, cW2, h, 256);
  k_ssd<<<BN / 4, 256, 0, stream>>>(h, cA2, ss, sd);
  k_ml<<<B_ * 4 * N_ / 4, 256, 0, stream>>>(ss, sd, m2, rl);
  k_attn<0><<<B_ * 4 * (N_ / 128), 256, 0, stream>>>(h, ss, sd, m2, rl, out_node);

  // ---- adjacency last (scratch lives in its output region) ----
  if (ws_ok) {
    k_adjf2<<<(ADJ_ELEMS / 4) / 256, 256, 0, stream>>>(cSt, out_adjf);
  } else {
    k_adjf<<<(ADJ_ELEMS / 4) / 256, 256, 0, stream>>>((const unsigned*)d_in[1], out_adjf);
  }

  if (mismatch >= 0) {
    float v = ldexpf(1024.f, mismatch);
    k_sentinel<<<1, 64, 0, stream>>>(out_node, v);
  }
}

// Round 11
// 702.602 us; speedup vs baseline: 2.9867x; 1.1119x over previous
//
#include <hip/hip_runtime.h>
#include <hip/hip_bf16.h>
#include <stdint.h>

static constexpr int B_  = 32;
static constexpr int E_  = 256;
static constexpr int N_  = 512;    // 2E
static constexpr int C_  = 256;    // H*F
static constexpr int BN  = B_ * N_;
static constexpr int NODE_ELEMS = B_ * N_ * C_;          // 4,194,304
static constexpr int ADJ_ELEMS  = B_ * 14 * N_ * N_;     // 117,440,512

#define LOG2E 1.44269504088896340736f

typedef __attribute__((ext_vector_type(8))) short v8bf;
typedef __attribute__((ext_vector_type(4))) float v4f;

__device__ __forceinline__ unsigned short f2bfbits(float f) {
  union { float f; unsigned u; } x; x.f = f;
  unsigned u = x.u;
  return (unsigned short)((u + 0x7FFFu + ((u >> 16) & 1u)) >> 16);
}

// ---------------- dtype-agnostic input conversion ----------------
struct ConvArgs {
  const void* src[15];
  void* dst[15];
  int n[15];
  int kind[15];   // 0 = float array, 1 = int array
};

__global__ __launch_bounds__(256) void k_conv2(ConvArgs a, const unsigned* fprobe,
                                               const unsigned* iprobe) {
  __shared__ int fk_s, ik_s;
  int t = threadIdx.x;
  if (t == 0) {
    int c_even = 0, c_lo = 0;
    for (int k = 0; k < 32; ++k) {
      unsigned w = fprobe[2 * k];
      unsigned e32 = (w >> 23) & 0xFFu;
      unsigned elo = (w >> 7) & 0xFFu;
      if (e32 >= 105u && e32 <= 135u) ++c_even;
      if (elo >= 105u && elo <= 135u) ++c_lo;
    }
    fk_s = (c_even < 16) ? 2 : ((c_lo >= 16) ? 1 : 0);   // 2=f64, 1=bf16, 0=f32
    int hi0 = 0;
    for (int k = 0; k < 32; ++k) if (iprobe[2 * k + 1] == 0u) ++hi0;
    ik_s = (hi0 >= 30) ? 1 : 0;                          // 1=i64, 0=i32
  }
  __syncthreads();
  int fk = fk_s, ik = ik_s;
  int arr = blockIdx.y;
  int n = a.n[arr], kind = a.kind[arr];
  for (int idx = blockIdx.x * 256 + t; idx < n; idx += gridDim.x * 256) {
    if (kind == 0) {
      float v;
      if (fk == 2) {
        v = (float)((const double*)a.src[arr])[idx];
      } else if (fk == 1) {
        unsigned short u = ((const unsigned short*)a.src[arr])[idx];
        union { unsigned u; float f; } c; c.u = (unsigned)u << 16; v = c.f;
      } else {
        v = ((const float*)a.src[arr])[idx];
      }
      ((float*)a.dst[arr])[idx] = v;
    } else {
      int v;
      if (ik == 1) v = (int)((const long long*)a.src[arr])[idx];
      else         v = ((const int*)a.src[arr])[idx];
      ((int*)a.dst[arr])[idx] = v;
    }
  }
}

// ---------------- node features: one thread per node, 64-thr blocks ----------------
__global__ __launch_bounds__(64) void k_feat2(
    const int* __restrict__ player, const float* __restrict__ Ax, const float* __restrict__ Ay,
    const float* __restrict__ Bx, const float* __restrict__ By,
    const float* __restrict__ emb, const float* __restrict__ Wc, const float* __restrict__ bc,
    const float* __restrict__ Wm, const float* __restrict__ bm, float* __restrict__ x) {
  int id = blockIdx.x * 64 + threadIdx.x;   // b*512 + n
  if (id >= BN) return;
  int b = id >> 9, n = id & 511;
  int e = n >> 1, side = n & 1;
  float cx = side ? Bx[b * E_ + e] : Ax[b * E_ + e];
  float cy = side ? By[b * E_ + e] : Ay[b * E_ + e];
  int pid = player[b * 2 + side];
  float ct[32];
  for (int k = 0; k < 32; ++k)
    ct[k] = fmaxf(fmaf(cx, Wc[k], fmaf(cy, Wc[32 + k], bc[k])), 0.f);
  for (int o = 0; o < 64; ++o) {
    float acc = bm[o];
    for (int c = 0; c < 32; ++c) acc = fmaf(ct[c], Wm[c * 64 + o], acc);
    for (int c = 0; c < 32; ++c) acc = fmaf(emb[pid * 32 + c], Wm[(32 + c) * 64 + o], acc);
    x[(size_t)id * 64 + o] = acc;
  }
}

// ---------------- tiled GEMM: h[BN,256] = x[BN,K] @ W[K,256] ----------------
__global__ __launch_bounds__(256) void k_gemm(
    const float* __restrict__ x, const float* __restrict__ W, float* __restrict__ h, int K) {
  __shared__ float xs[64 * 64];
  __shared__ float wt[64 * 64];
  int row0 = blockIdx.x * 64;
  int col0 = blockIdx.y * 64;
  int t = threadIdx.x;
  int tx = t & 15, ty = t >> 4;
  float acc[4][4] = {};
  for (int kt = 0; kt < K; kt += 64) {
    #pragma unroll
    for (int q = 0; q < 4; ++q) {
      int v = q * 256 + t;            // float4 chunk id 0..1023
      int r = v >> 4, c = (v & 15) * 4;
      *(float4*)&xs[r * 64 + c] = *(const float4*)&x[(size_t)(row0 + r) * K + kt + c];
      *(float4*)&wt[r * 64 + c] = *(const float4*)&W[(size_t)(kt + r) * C_ + col0 + c];
    }
    __syncthreads();
    #pragma unroll 4
    for (int k = 0; k < 64; ++k) {
      float xv[4];
      #pragma unroll
      for (int r = 0; r < 4; ++r) xv[r] = xs[(ty * 4 + r) * 64 + k];
      float4 wf = *(const float4*)&wt[k * 64 + tx * 4];
      #pragma unroll
      for (int r = 0; r < 4; ++r) {
        acc[r][0] = fmaf(xv[r], wf.x, acc[r][0]);
        acc[r][1] = fmaf(xv[r], wf.y, acc[r][1]);
        acc[r][2] = fmaf(xv[r], wf.z, acc[r][2]);
        acc[r][3] = fmaf(xv[r], wf.w, acc[r][3]);
      }
    }
    __syncthreads();
  }
  #pragma unroll
  for (int r = 0; r < 4; ++r) {
    int row = row0 + ty * 4 + r;
    float4 o = make_float4(acc[r][0], acc[r][1], acc[r][2], acc[r][3]);
    *(float4*)&h[(size_t)row * C_ + col0 + tx * 4] = o;
  }
}

// ---------------- s_src/s_dst: [B,H,N] ----------------
__global__ __launch_bounds__(256) void k_ssd(
    const float* __restrict__ h, const float* __restrict__ att,
    float* __restrict__ ss, float* __restrict__ sd) {
  int t = threadIdx.x;
  int wv = t >> 6, l = t & 63;
  int row = blockIdx.x * 4 + wv;       // b*512+n
  int b = row >> 9, n = row & 511;
  #pragma unroll
  for (int hd = 0; hd < 4; ++hd) {
    float v = h[(size_t)row * C_ + hd * 64 + l];
    float s1 = v * att[hd * 128 + l];
    float s2 = v * att[hd * 128 + 64 + l];
    #pragma unroll
    for (int d = 32; d > 0; d >>= 1) {
      s1 += __shfl_xor(s1, d, 64);
      s2 += __shfl_xor(s2, d, 64);
    }
    if (l == 0) {
      int idx = (b * 4 + hd) * N_ + n;
      ss[idx] = s1; sd[idx] = s2;
    }
  }
}

// ---------------- softmax stats: m2 = m*log2e, rl = 1/l ----------------
__global__ __launch_bounds__(256) void k_ml(
    const float* __restrict__ ss, const float* __restrict__ sd,
    float* __restrict__ m2, float* __restrict__ rl) {
  int t = threadIdx.x;
  int wv = t >> 6, l = t & 63;
  int row = blockIdx.x * 4 + wv;       // bh*512 + i
  int bh = row >> 9, i = row & 511;
  const float* sdb = sd + (size_t)bh * N_;
  float mx = -1e30f;
  #pragma unroll
  for (int q = 0; q < 8; ++q) mx = fmaxf(mx, sdb[q * 64 + l]);
  #pragma unroll
  for (int d = 32; d > 0; d >>= 1) mx = fmaxf(mx, __shfl_xor(mx, d, 64));
  float ssi = ss[row];
  float s = ssi + mx;
  float mm2 = fmaxf(s, 0.2f * s) * LOG2E;   // leaky monotone -> row-max bound
  float acc = 0.f;
  #pragma unroll
  for (int q = 0; q < 8; ++q) {
    int j = q * 64 + l;
    float sc = ssi + sdb[j];
    sc = fmaxf(sc, 0.2f * sc);
    float e = exp2f(fmaf(sc, LOG2E, -mm2));
    acc += (j == i) ? 0.f : e;
  }
  #pragma unroll
  for (int d = 32; d > 0; d >>= 1) acc += __shfl_xor(acc, d, 64);
  if (l == 0) { m2[row] = mm2; rl[row] = 1.f / acc; }
}

// ---------------- MFMA attention: out[b,i,hd*64+f] = (P @ h_slice) * rl ----------------
// Wave w owns i in [i0+w*32, +32). A-frags (P) built in registers (no P LDS);
// h staged bf16 f-major with pad 8 -> B-frag = one ds_read_b128.
template <int RELU>
__global__ __launch_bounds__(256) void k_attn_mfma(
    const float* __restrict__ h, const float* __restrict__ ss, const float* __restrict__ sd,
    const float* __restrict__ m2, const float* __restrict__ rl, float* __restrict__ outf) {
  __shared__ unsigned short hs[64 * 72];   // hs[f*72 + j], bf16
  __shared__ float sdl[64];
  int blk = blockIdx.x;
  int it = blk & 3, hd = (blk >> 2) & 3, b = blk >> 4;
  int i0 = it * 128;
  int bh = b * 4 + hd;
  int t = threadIdx.x;
  int w = t >> 6, l = t & 63;
  int lane16 = l & 15, quad = l >> 4;
  float ss_s[2], m2_s[2];
  #pragma unroll
  for (int s = 0; s < 2; ++s) {
    int i = i0 + w * 32 + s * 16 + lane16;
    ss_s[s] = ss[(size_t)bh * N_ + i];
    m2_s[s] = m2[(size_t)bh * N_ + i];
  }
  v4f acc[2][4] = {};   // [s][fsub]
  for (int jt = 0; jt < 8; ++jt) {
    int j0 = jt * 64;
    // stage h -> hs[f][j] bf16 (transpose during staging)
    #pragma unroll
    for (int q = 0; q < 4; ++q) {
      int v = q * 256 + t;             // chunk: j = v>>4, f0 = (v&15)*4
      int j = v >> 4, f0 = (v & 15) * 4;
      float4 hv = *(const float4*)&h[(size_t)(b * N_ + j0 + j) * C_ + hd * 64 + f0];
      hs[(f0 + 0) * 72 + j] = f2bfbits(hv.x);
      hs[(f0 + 1) * 72 + j] = f2bfbits(hv.y);
      hs[(f0 + 2) * 72 + j] = f2bfbits(hv.z);
      hs[(f0 + 3) * 72 + j] = f2bfbits(hv.w);
    }
    if (t < 64) sdl[t] = sd[(size_t)bh * N_ + j0 + t];
    __syncthreads();
    #pragma unroll
    for (int ks = 0; ks < 2; ++ks) {
      int kb = ks * 32;
      // A fragments: A[m = lane16][k = quad*8+q] = P[i][j]
      v8bf afr[2];
      #pragma unroll
      for (int s = 0; s < 2; ++s) {
        int i = i0 + w * 32 + s * 16 + lane16;
        #pragma unroll
        for (int q = 0; q < 8; ++q) {
          int j = kb + quad * 8 + q;
          float sv = ss_s[s] + sdl[j];
          float sc = fmaxf(sv, 0.2f * sv);
          float p = exp2f(fmaf(sc, LOG2E, -m2_s[s]));
          if (i == j0 + j) p = 0.f;
          afr[s][q] = (short)f2bfbits(p);
        }
      }
      // B fragments + MFMA: B[k = quad*8+q][n = lane16], f = fs*16 + lane16
      #pragma unroll
      for (int fs = 0; fs < 4; ++fs) {
        v8bf bfr = *(const v8bf*)&hs[(fs * 16 + lane16) * 72 + kb + quad * 8];
        acc[0][fs] = __builtin_amdgcn_mfma_f32_16x16x32_bf16(afr[0], bfr, acc[0][fs], 0, 0, 0);
        acc[1][fs] = __builtin_amdgcn_mfma_f32_16x16x32_bf16(afr[1], bfr, acc[1][fs], 0, 0, 0);
      }
    }
    __syncthreads();
  }
  // epilogue: C/D layout col = lane16 (f), row = quad*4 + reg (i)
  #pragma unroll
  for (int s = 0; s < 2; ++s) {
    #pragma unroll
    for (int r = 0; r < 4; ++r) {
      int i = i0 + w * 32 + s * 16 + quad * 4 + r;
      float scale = rl[(size_t)bh * N_ + i];
      #pragma unroll
      for (int fs = 0; fs < 4; ++fs) {
        int f = fs * 16 + lane16;
        float vv = acc[s][fs][r] * scale;
        if constexpr (RELU) vv = fmaxf(vv, 0.f);
        outf[(size_t)(b * N_ + i) * C_ + hd * 64 + f] = vv;
      }
    }
  }
}

// ---------------- adjacency v2: pure analytic fill from converted i32 st ----------------
__global__ __launch_bounds__(256) void k_adjf2(
    const int* __restrict__ st, float* __restrict__ adj) {
  int chunk = blockIdx.x * 256 + threadIdx.x;   // float4 id
  int j0 = (chunk & 127) << 2;
  int rowid = chunk >> 7;
  int i = rowid & 511;
  int plane = rowid >> 9;                        // b*14 + r
  int r = plane % 14;
  int b = plane / 14;
  float vals[4];
  #pragma unroll
  for (int q = 0; q < 4; ++q) {
    int j = j0 + q;
    int d = j - i;
    int ad = d < 0 ? -d : d;
    int mn = d < 0 ? j : i;
    int m4 = mn & 3;
    float v = 0.f;
    if (r == 13) {
      bool excl = (d == 0) || (ad == 2) || (ad == 3 && m4 == 0) || (ad == 1 && m4 == 3);
      v = excl ? 0.f : 1.f;
    } else if (r == 11) {
      v = (ad == 2 && (m4 == 0 || m4 == 3)) ? 1.f : 0.f;
    } else if (r == 12) {
      v = (ad == 2 && (m4 == 1 || m4 == 2)) ? 1.f : 0.f;
    } else {
      bool sp = (ad == 3 && m4 == 0) || (ad == 1 && m4 == 3);
      if (sp) v = (st[b * 255 + (mn >> 1)] == r) ? 1.f : 0.f;
    }
    vals[q] = v;
  }
  *(float4*)&adj[(size_t)chunk * 4] = make_float4(vals[0], vals[1], vals[2], vals[3]);
}

// ---------------- adjacency fallback: raw input + per-block sniff ----------------
__global__ __launch_bounds__(256) void k_adjf(
    const unsigned* __restrict__ st_raw, float* __restrict__ adj) {
  __shared__ int i64_s;
  if (threadIdx.x == 0) {
    int hi0 = 0;
    for (int k = 0; k < 32; ++k) if (st_raw[2 * k + 1] == 0u) ++hi0;
    i64_s = (hi0 >= 30) ? 1 : 0;
  }
  __syncthreads();
  int is64 = i64_s;
  int chunk = blockIdx.x * 256 + threadIdx.x;
  int j0 = (chunk & 127) << 2;
  int rowid = chunk >> 7;
  int i = rowid & 511;
  int plane = rowid >> 9;
  int r = plane % 14;
  int b = plane / 14;
  float vals[4];
  #pragma unroll
  for (int q = 0; q < 4; ++q) {
    int j = j0 + q;
    int d = j - i;
    int ad = d < 0 ? -d : d;
    int mn = d < 0 ? j : i;
    int m4 = mn & 3;
    float v = 0.f;
    if (r == 13) {
      bool excl = (d == 0) || (ad == 2) || (ad == 3 && m4 == 0) || (ad == 1 && m4 == 3);
      v = excl ? 0.f : 1.f;
    } else if (r == 11) {
      v = (ad == 2 && (m4 == 0 || m4 == 3)) ? 1.f : 0.f;
    } else if (r == 12) {
      v = (ad == 2 && (m4 == 1 || m4 == 2)) ? 1.f : 0.f;
    } else {
      bool sp = (ad == 3 && m4 == 0) || (ad == 1 && m4 == 3);
      if (sp) {
        int e = b * 255 + (mn >> 1);
        int stv = is64 ? (int)st_raw[2 * e] : (int)st_raw[e];
        v = (stv == r) ? 1.f : 0.f;
      }
    }
    vals[q] = v;
  }
  *(float4*)&adj[(size_t)chunk * 4] = make_float4(vals[0], vals[1], vals[2], vals[3]);
}

// ---------------- sentinel ----------------
__global__ void k_sentinel(float* out, float v) {
  if (threadIdx.x == 0 && blockIdx.x == 0) out[0] = v;
}

extern "C" void kernel_launch(void* const* d_in, const int* in_sizes, int n_in,
                              void* d_out, int out_size, void* d_ws, size_t ws_size,
                              hipStream_t stream) {
  static const int expA[16] = {64,8160,8192,8192,8192,8192,1,1120,64,32,4096,64,16384,512,65536,512};
  static const int expB[15] = {64,8160,8192,8192,8192,8192,1120,64,32,4096,64,16384,512,65536,512};
  int mismatch = -1;
  int base = 7;
  if (n_in == 16) {
    base = 7;
    for (int i = 0; i < 16; ++i) if (in_sizes[i] != expA[i]) { mismatch = i; break; }
  } else if (n_in == 15) {
    base = 6;
    for (int i = 0; i < 15; ++i) if (in_sizes[i] != expB[i]) { mismatch = i; break; }
  } else {
    mismatch = 17;
  }
  if (mismatch < 0 && out_size != NODE_ELEMS + ADJ_ELEMS) mismatch = 16;

  float* out_node = (float*)d_out;                 // f32 output
  float* out_adjf = out_node + NODE_ELEMS;

  // Scratch carved from the f32 adj output region (470 MB); adj written last.
  char* scr = (char*)out_adjf;
  float* x  = (float*)(scr);                       //  4 MB
  float* h  = (float*)(scr + (size_t)( 4u << 20)); // 16 MB
  float* x2 = (float*)(scr + (size_t)(24u << 20)); // 16 MB
  float* ss = (float*)(scr + (size_t)(44u << 20)); // 256 KB
  float* sd = (float*)(scr + (size_t)(45u << 20)); // 256 KB
  float* m2 = (float*)(scr + (size_t)(46u << 20)); // 256 KB
  float* rl = (float*)(scr + (size_t)(47u << 20)); // 256 KB
  float* cv = (float*)(scr + (size_t)(48u << 20)); // converted inputs

  float* cAx  = cv + 0;
  float* cAy  = cv + 8192;
  float* cBx  = cv + 16384;
  float* cBy  = cv + 24576;
  float* cEmb = cv + 32768;
  float* cWc  = cv + 33888;
  float* cbc  = cv + 33952;
  float* cWm  = cv + 33984;
  float* cbm  = cv + 38080;
  float* cW1  = cv + 38144;
  float* cA1  = cv + 54528;
  float* cW2  = cv + 55040;
  float* cA2  = cv + 120576;
  int*   cPl  = (int*)(cv + 121088);

  bool ws_ok = (ws_size >= 8160 * sizeof(int));
  int* cSt = ws_ok ? (int*)d_ws : nullptr;

  ConvArgs a;
  a.src[0]  = d_in[2];        a.dst[0]  = cAx;  a.n[0]  = 8192;  a.kind[0]  = 0;
  a.src[1]  = d_in[3];        a.dst[1]  = cAy;  a.n[1]  = 8192;  a.kind[1]  = 0;
  a.src[2]  = d_in[4];        a.dst[2]  = cBx;  a.n[2]  = 8192;  a.kind[2]  = 0;
  a.src[3]  = d_in[5];        a.dst[3]  = cBy;  a.n[3]  = 8192;  a.kind[3]  = 0;
  a.src[4]  = d_in[base + 0]; a.dst[4]  = cEmb; a.n[4]  = 1120;  a.kind[4]  = 0;
  a.src[5]  = d_in[base + 1]; a.dst[5]  = cWc;  a.n[5]  = 64;    a.kind[5]  = 0;
  a.src[6]  = d_in[base + 2]; a.dst[6]  = cbc;  a.n[6]  = 32;    a.kind[6]  = 0;
  a.src[7]  = d_in[base + 3]; a.dst[7]  = cWm;  a.n[7]  = 4096;  a.kind[7]  = 0;
  a.src[8]  = d_in[base + 4]; a.dst[8]  = cbm;  a.n[8]  = 64;    a.kind[8]  = 0;
  a.src[9]  = d_in[base + 5]; a.dst[9]  = cW1;  a.n[9]  = 16384; a.kind[9]  = 0;
  a.src[10] = d_in[base + 6]; a.dst[10] = cA1;  a.n[10] = 512;   a.kind[10] = 0;
  a.src[11] = d_in[base + 7]; a.dst[11] = cW2;  a.n[11] = 65536; a.kind[11] = 0;
  a.src[12] = d_in[base + 8]; a.dst[12] = cA2;  a.n[12] = 512;   a.kind[12] = 0;
  a.src[13] = d_in[0];        a.dst[13] = cPl;  a.n[13] = 64;    a.kind[13] = 1;
  a.src[14] = d_in[1];        a.dst[14] = ws_ok ? (void*)cSt : (void*)cPl;
  a.n[14] = ws_ok ? 8160 : 0; a.kind[14] = 1;

  k_conv2<<<dim3(64, 15), 256, 0, stream>>>(a, (const unsigned*)d_in[base + 3],
                                            (const unsigned*)d_in[0]);

  k_feat2<<<BN / 64, 64, 0, stream>>>(cPl, cAx, cAy, cBx, cBy, cEmb, cWc, cbc, cWm, cbm, x);

  // ---- layer 1 ----
  k_gemm<<<dim3(BN / 64, 4), 256, 0, stream>>>(x, cW1, h, 64);
  k_ssd<<<BN / 4, 256, 0, stream>>>(h, cA1, ss, sd);
  k_ml<<<B_ * 4 * N_ / 4, 256, 0, stream>>>(ss, sd, m2, rl);
  k_attn_mfma<1><<<B_ * 4 * (N_ / 128), 256, 0, stream>>>(h, ss, sd, m2, rl, x2);

  // ---- layer 2 ----
  k_gemm<<<dim3(BN / 64, 4), 256, 0, stream>>>(x2, cW2, h, 256);
  k_ssd<<<BN / 4, 256, 0, stream>>>(h, cA2, ss, sd);
  k_ml<<<B_ * 4 * N_ / 4, 256, 0, stream>>>(ss, sd, m2, rl);
  k_attn_mfma<0><<<B_ * 4 * (N_ / 128), 256, 0, stream>>>(h, ss, sd, m2, rl, out_node);

  // ---- adjacency last (scratch lives in its output region) ----
  if (ws_ok) {
    k_adjf2<<<(ADJ_ELEMS / 4) / 256, 256, 0, stream>>>(cSt, out_adjf);
  } else {
    k_adjf<<<(ADJ_ELEMS / 4) / 256, 256, 0, stream>>>((const unsigned*)d_in[1], out_adjf);
  }

  if (mismatch >= 0) {
    float v = ldexpf(1024.f, mismatch);
    k_sentinel<<<1, 64, 0, stream>>>(out_node, v);
  }
}

// Round 12
// 647.814 us; speedup vs baseline: 3.2392x; 1.0846x over previous
//
#include <hip/hip_runtime.h>
#include <hip/hip_bf16.h>
#include <stdint.h>

static constexpr int B_  = 32;
static constexpr int E_  = 256;
static constexpr int N_  = 512;    // 2E
static constexpr int C_  = 256;    // H*F
static constexpr int BN  = B_ * N_;
static constexpr int NODE_ELEMS = B_ * N_ * C_;          // 4,194,304
static constexpr int ADJ_ELEMS  = B_ * 14 * N_ * N_;     // 117,440,512

#define LOG2E 1.44269504088896340736f

typedef __attribute__((ext_vector_type(8))) short v8bf;
typedef __attribute__((ext_vector_type(4))) float v4f;

__device__ __forceinline__ unsigned short f2bfbits(float f) {
  union { float f; unsigned u; } x; x.f = f;
  unsigned u = x.u;
  return (unsigned short)((u + 0x7FFFu + ((u >> 16) & 1u)) >> 16);
}

// ---------------- dtype-agnostic input conversion ----------------
struct ConvArgs {
  const void* src[15];
  void* dst[15];
  int n[15];
  int kind[15];   // 0 = float array, 1 = int array
};

__global__ __launch_bounds__(256) void k_conv2(ConvArgs a, const unsigned* fprobe,
                                               const unsigned* iprobe) {
  __shared__ int fk_s, ik_s;
  int t = threadIdx.x;
  if (t == 0) {
    int c_even = 0, c_lo = 0;
    for (int k = 0; k < 32; ++k) {
      unsigned w = fprobe[2 * k];
      unsigned e32 = (w >> 23) & 0xFFu;
      unsigned elo = (w >> 7) & 0xFFu;
      if (e32 >= 105u && e32 <= 135u) ++c_even;
      if (elo >= 105u && elo <= 135u) ++c_lo;
    }
    fk_s = (c_even < 16) ? 2 : ((c_lo >= 16) ? 1 : 0);   // 2=f64, 1=bf16, 0=f32
    int hi0 = 0;
    for (int k = 0; k < 32; ++k) if (iprobe[2 * k + 1] == 0u) ++hi0;
    ik_s = (hi0 >= 30) ? 1 : 0;                          // 1=i64, 0=i32
  }
  __syncthreads();
  int fk = fk_s, ik = ik_s;
  int arr = blockIdx.y;
  int n = a.n[arr], kind = a.kind[arr];
  for (int idx = blockIdx.x * 256 + t; idx < n; idx += gridDim.x * 256) {
    if (kind == 0) {
      float v;
      if (fk == 2) {
        v = (float)((const double*)a.src[arr])[idx];
      } else if (fk == 1) {
        unsigned short u = ((const unsigned short*)a.src[arr])[idx];
        union { unsigned u; float f; } c; c.u = (unsigned)u << 16; v = c.f;
      } else {
        v = ((const float*)a.src[arr])[idx];
      }
      ((float*)a.dst[arr])[idx] = v;
    } else {
      int v;
      if (ik == 1) v = (int)((const long long*)a.src[arr])[idx];
      else         v = ((const int*)a.src[arr])[idx];
      ((int*)a.dst[arr])[idx] = v;
    }
  }
}

// ---------------- node features: one thread per node, 64-thr blocks ----------------
__global__ __launch_bounds__(64) void k_feat2(
    const int* __restrict__ player, const float* __restrict__ Ax, const float* __restrict__ Ay,
    const float* __restrict__ Bx, const float* __restrict__ By,
    const float* __restrict__ emb, const float* __restrict__ Wc, const float* __restrict__ bc,
    const float* __restrict__ Wm, const float* __restrict__ bm, float* __restrict__ x) {
  int id = blockIdx.x * 64 + threadIdx.x;   // b*512 + n
  if (id >= BN) return;
  int b = id >> 9, n = id & 511;
  int e = n >> 1, side = n & 1;
  float cx = side ? Bx[b * E_ + e] : Ax[b * E_ + e];
  float cy = side ? By[b * E_ + e] : Ay[b * E_ + e];
  int pid = player[b * 2 + side];
  float ct[32];
  for (int k = 0; k < 32; ++k)
    ct[k] = fmaxf(fmaf(cx, Wc[k], fmaf(cy, Wc[32 + k], bc[k])), 0.f);
  for (int o = 0; o < 64; ++o) {
    float acc = bm[o];
    for (int c = 0; c < 32; ++c) acc = fmaf(ct[c], Wm[c * 64 + o], acc);
    for (int c = 0; c < 32; ++c) acc = fmaf(emb[pid * 32 + c], Wm[(32 + c) * 64 + o], acc);
    x[(size_t)id * 64 + o] = acc;
  }
}

// ---------------- tiled GEMM + fused GAT score epilogue ----------------
// h[BN,256] = x[BN,K] @ W[K,256]; gridDim.y==4 -> block col range == head hd.
// Epilogue: ss/sd[(b*4+hd)*512+n] = h_row . att[hd][:64] / att[hd][64:].
__global__ __launch_bounds__(256) void k_gemm(
    const float* __restrict__ x, const float* __restrict__ W, float* __restrict__ h, int K,
    const float* __restrict__ att, float* __restrict__ ssO, float* __restrict__ sdO) {
  __shared__ float xs[64 * 64];
  __shared__ float wt[64 * 64];
  int row0 = blockIdx.x * 64;
  int col0 = blockIdx.y * 64;
  int hd = blockIdx.y;
  int t = threadIdx.x;
  int tx = t & 15, ty = t >> 4;
  float acc[4][4] = {};
  for (int kt = 0; kt < K; kt += 64) {
    #pragma unroll
    for (int q = 0; q < 4; ++q) {
      int v = q * 256 + t;            // float4 chunk id 0..1023
      int r = v >> 4, c = (v & 15) * 4;
      *(float4*)&xs[r * 64 + c] = *(const float4*)&x[(size_t)(row0 + r) * K + kt + c];
      *(float4*)&wt[r * 64 + c] = *(const float4*)&W[(size_t)(kt + r) * C_ + col0 + c];
    }
    __syncthreads();
    #pragma unroll 4
    for (int k = 0; k < 64; ++k) {
      float xv[4];
      #pragma unroll
      for (int r = 0; r < 4; ++r) xv[r] = xs[(ty * 4 + r) * 64 + k];
      float4 wf = *(const float4*)&wt[k * 64 + tx * 4];
      #pragma unroll
      for (int r = 0; r < 4; ++r) {
        acc[r][0] = fmaf(xv[r], wf.x, acc[r][0]);
        acc[r][1] = fmaf(xv[r], wf.y, acc[r][1]);
        acc[r][2] = fmaf(xv[r], wf.z, acc[r][2]);
        acc[r][3] = fmaf(xv[r], wf.w, acc[r][3]);
      }
    }
    __syncthreads();
  }
  #pragma unroll
  for (int r = 0; r < 4; ++r) {
    int row = row0 + ty * 4 + r;
    float4 o = make_float4(acc[r][0], acc[r][1], acc[r][2], acc[r][3]);
    *(float4*)&h[(size_t)row * C_ + col0 + tx * 4] = o;
  }
  // fused score epilogue
  float attS[4], attD[4];
  #pragma unroll
  for (int c = 0; c < 4; ++c) {
    attS[c] = att[hd * 128 + tx * 4 + c];
    attD[c] = att[hd * 128 + 64 + tx * 4 + c];
  }
  #pragma unroll
  for (int r = 0; r < 4; ++r) {
    float p1 = acc[r][0] * attS[0] + acc[r][1] * attS[1] + acc[r][2] * attS[2] + acc[r][3] * attS[3];
    float p2 = acc[r][0] * attD[0] + acc[r][1] * attD[1] + acc[r][2] * attD[2] + acc[r][3] * attD[3];
    #pragma unroll
    for (int d = 8; d > 0; d >>= 1) {
      p1 += __shfl_xor(p1, d, 16);
      p2 += __shfl_xor(p2, d, 16);
    }
    if (tx == 0) {
      int row = row0 + ty * 4 + r;
      int bb = row >> 9, nn = row & 511;
      int idx = (bb * 4 + hd) * N_ + nn;
      ssO[idx] = p1; sdO[idx] = p2;
    }
  }
}

// ---------------- MFMA attention v2 (self-contained softmax stats) ----------------
// Stage full sd row; block-max -> m2 bound; accumulate f32 row-sum of P during
// A-frag build; rescale at epilogue. Wave w owns i in [i0+w*32, +32).
template <int RELU>
__global__ __launch_bounds__(256) void k_attn_mfma2(
    const float* __restrict__ h, const float* __restrict__ ss, const float* __restrict__ sd,
    float* __restrict__ outf) {
  __shared__ unsigned short hs[64 * 72];   // hs[f*72 + j], bf16
  __shared__ float sdl[512];
  __shared__ float red[4];
  __shared__ float ls[4][32];
  int blk = blockIdx.x;
  int it = blk & 3, hd = (blk >> 2) & 3, b = blk >> 4;
  int i0 = it * 128, bh = b * 4 + hd;
  int t = threadIdx.x, w = t >> 6, l = t & 63;
  int lane16 = l & 15, quad = l >> 4;
  float v0 = sd[(size_t)bh * N_ + t];
  float v1 = sd[(size_t)bh * N_ + 256 + t];
  sdl[t] = v0; sdl[256 + t] = v1;
  float mx = fmaxf(v0, v1);
  #pragma unroll
  for (int d = 32; d > 0; d >>= 1) mx = fmaxf(mx, __shfl_xor(mx, d, 64));
  if (l == 0) red[w] = mx;
  __syncthreads();
  mx = fmaxf(fmaxf(red[0], red[1]), fmaxf(red[2], red[3]));
  float ss_s[2], m2_s[2], lsum[2] = {0.f, 0.f};
  #pragma unroll
  for (int s = 0; s < 2; ++s) {
    int i = i0 + w * 32 + s * 16 + lane16;
    ss_s[s] = ss[(size_t)bh * N_ + i];
    float sv = ss_s[s] + mx;
    m2_s[s] = fmaxf(sv, 0.2f * sv) * LOG2E;   // leaky monotone -> row-max bound
  }
  v4f acc[2][4] = {};   // [s][fsub]
  for (int jt = 0; jt < 8; ++jt) {
    int j0 = jt * 64;
    #pragma unroll
    for (int q = 0; q < 4; ++q) {
      int v = q * 256 + t;             // chunk: j = v>>4, f0 = (v&15)*4
      int j = v >> 4, f0 = (v & 15) * 4;
      float4 hv = *(const float4*)&h[(size_t)(b * N_ + j0 + j) * C_ + hd * 64 + f0];
      hs[(f0 + 0) * 72 + j] = f2bfbits(hv.x);
      hs[(f0 + 1) * 72 + j] = f2bfbits(hv.y);
      hs[(f0 + 2) * 72 + j] = f2bfbits(hv.z);
      hs[(f0 + 3) * 72 + j] = f2bfbits(hv.w);
    }
    __syncthreads();
    #pragma unroll
    for (int ks = 0; ks < 2; ++ks) {
      int kb = ks * 32;
      v8bf afr[2];
      #pragma unroll
      for (int s = 0; s < 2; ++s) {
        int i = i0 + w * 32 + s * 16 + lane16;
        #pragma unroll
        for (int q = 0; q < 8; ++q) {
          int j = j0 + kb + quad * 8 + q;   // global j
          float sv = ss_s[s] + sdl[j];
          float sc = fmaxf(sv, 0.2f * sv);
          float p = exp2f(fmaf(sc, LOG2E, -m2_s[s]));
          if (i == j) p = 0.f;
          lsum[s] += p;
          afr[s][q] = (short)f2bfbits(p);
        }
      }
      #pragma unroll
      for (int fs = 0; fs < 4; ++fs) {
        v8bf bfr = *(const v8bf*)&hs[(fs * 16 + lane16) * 72 + kb + quad * 8];
        acc[0][fs] = __builtin_amdgcn_mfma_f32_16x16x32_bf16(afr[0], bfr, acc[0][fs], 0, 0, 0);
        acc[1][fs] = __builtin_amdgcn_mfma_f32_16x16x32_bf16(afr[1], bfr, acc[1][fs], 0, 0, 0);
      }
    }
    __syncthreads();
  }
  // cross-quad reduce: full row sum of P per (s, lane16); transpose via LDS
  #pragma unroll
  for (int s = 0; s < 2; ++s) {
    lsum[s] += __shfl_xor(lsum[s], 16, 64);
    lsum[s] += __shfl_xor(lsum[s], 32, 64);
    if (quad == 0) ls[w][s * 16 + lane16] = lsum[s];
  }
  __syncthreads();
  // epilogue: C/D layout col = lane16 (f), row = quad*4 + reg (i)
  #pragma unroll
  for (int s = 0; s < 2; ++s) {
    #pragma unroll
    for (int r = 0; r < 4; ++r) {
      int i = i0 + w * 32 + s * 16 + quad * 4 + r;
      float scale = 1.f / ls[w][s * 16 + quad * 4 + r];
      #pragma unroll
      for (int fs = 0; fs < 4; ++fs) {
        int f = fs * 16 + lane16;
        float vv = acc[s][fs][r] * scale;
        if constexpr (RELU) vv = fmaxf(vv, 0.f);
        outf[(size_t)(b * N_ + i) * C_ + hd * 64 + f] = vv;
      }
    }
  }
}

// ---------------- adjacency v2: pure analytic fill from converted i32 st ----------------
__global__ __launch_bounds__(256) void k_adjf2(
    const int* __restrict__ st, float* __restrict__ adj) {
  int chunk = blockIdx.x * 256 + threadIdx.x;   // float4 id
  int j0 = (chunk & 127) << 2;
  int rowid = chunk >> 7;
  int i = rowid & 511;
  int plane = rowid >> 9;                        // b*14 + r
  int r = plane % 14;
  int b = plane / 14;
  float vals[4];
  #pragma unroll
  for (int q = 0; q < 4; ++q) {
    int j = j0 + q;
    int d = j - i;
    int ad = d < 0 ? -d : d;
    int mn = d < 0 ? j : i;
    int m4 = mn & 3;
    float v = 0.f;
    if (r == 13) {
      bool excl = (d == 0) || (ad == 2) || (ad == 3 && m4 == 0) || (ad == 1 && m4 == 3);
      v = excl ? 0.f : 1.f;
    } else if (r == 11) {
      v = (ad == 2 && (m4 == 0 || m4 == 3)) ? 1.f : 0.f;
    } else if (r == 12) {
      v = (ad == 2 && (m4 == 1 || m4 == 2)) ? 1.f : 0.f;
    } else {
      bool sp = (ad == 3 && m4 == 0) || (ad == 1 && m4 == 3);
      if (sp) v = (st[b * 255 + (mn >> 1)] == r) ? 1.f : 0.f;
    }
    vals[q] = v;
  }
  *(float4*)&adj[(size_t)chunk * 4] = make_float4(vals[0], vals[1], vals[2], vals[3]);
}

// ---------------- adjacency fallback: raw input + per-block sniff ----------------
__global__ __launch_bounds__(256) void k_adjf(
    const unsigned* __restrict__ st_raw, float* __restrict__ adj) {
  __shared__ int i64_s;
  if (threadIdx.x == 0) {
    int hi0 = 0;
    for (int k = 0; k < 32; ++k) if (st_raw[2 * k + 1] == 0u) ++hi0;
    i64_s = (hi0 >= 30) ? 1 : 0;
  }
  __syncthreads();
  int is64 = i64_s;
  int chunk = blockIdx.x * 256 + threadIdx.x;
  int j0 = (chunk & 127) << 2;
  int rowid = chunk >> 7;
  int i = rowid & 511;
  int plane = rowid >> 9;
  int r = plane % 14;
  int b = plane / 14;
  float vals[4];
  #pragma unroll
  for (int q = 0; q < 4; ++q) {
    int j = j0 + q;
    int d = j - i;
    int ad = d < 0 ? -d : d;
    int mn = d < 0 ? j : i;
    int m4 = mn & 3;
    float v = 0.f;
    if (r == 13) {
      bool excl = (d == 0) || (ad == 2) || (ad == 3 && m4 == 0) || (ad == 1 && m4 == 3);
      v = excl ? 0.f : 1.f;
    } else if (r == 11) {
      v = (ad == 2 && (m4 == 0 || m4 == 3)) ? 1.f : 0.f;
    } else if (r == 12) {
      v = (ad == 2 && (m4 == 1 || m4 == 2)) ? 1.f : 0.f;
    } else {
      bool sp = (ad == 3 && m4 == 0) || (ad == 1 && m4 == 3);
      if (sp) {
        int e = b * 255 + (mn >> 1);
        int stv = is64 ? (int)st_raw[2 * e] : (int)st_raw[e];
        v = (stv == r) ? 1.f : 0.f;
      }
    }
    vals[q] = v;
  }
  *(float4*)&adj[(size_t)chunk * 4] = make_float4(vals[0], vals[1], vals[2], vals[3]);
}

// ---------------- sentinel ----------------
__global__ void k_sentinel(float* out, float v) {
  if (threadIdx.x == 0 && blockIdx.x == 0) out[0] = v;
}

extern "C" void kernel_launch(void* const* d_in, const int* in_sizes, int n_in,
                              void* d_out, int out_size, void* d_ws, size_t ws_size,
                              hipStream_t stream) {
  static const int expA[16] = {64,8160,8192,8192,8192,8192,1,1120,64,32,4096,64,16384,512,65536,512};
  static const int expB[15] = {64,8160,8192,8192,8192,8192,1120,64,32,4096,64,16384,512,65536,512};
  int mismatch = -1;
  int base = 7;
  if (n_in == 16) {
    base = 7;
    for (int i = 0; i < 16; ++i) if (in_sizes[i] != expA[i]) { mismatch = i; break; }
  } else if (n_in == 15) {
    base = 6;
    for (int i = 0; i < 15; ++i) if (in_sizes[i] != expB[i]) { mismatch = i; break; }
  } else {
    mismatch = 17;
  }
  if (mismatch < 0 && out_size != NODE_ELEMS + ADJ_ELEMS) mismatch = 16;

  float* out_node = (float*)d_out;                 // f32 output
  float* out_adjf = out_node + NODE_ELEMS;

  // Scratch carved from the f32 adj output region (470 MB); adj written last.
  char* scr = (char*)out_adjf;
  float* x  = (float*)(scr);                       //  4 MB
  float* h  = (float*)(scr + (size_t)( 4u << 20)); // 16 MB
  float* x2 = (float*)(scr + (size_t)(24u << 20)); // 16 MB
  float* ss = (float*)(scr + (size_t)(44u << 20)); // 256 KB
  float* sd = (float*)(scr + (size_t)(45u << 20)); // 256 KB
  float* cv = (float*)(scr + (size_t)(48u << 20)); // converted inputs

  float* cAx  = cv + 0;
  float* cAy  = cv + 8192;
  float* cBx  = cv + 16384;
  float* cBy  = cv + 24576;
  float* cEmb = cv + 32768;
  float* cWc  = cv + 33888;
  float* cbc  = cv + 33952;
  float* cWm  = cv + 33984;
  float* cbm  = cv + 38080;
  float* cW1  = cv + 38144;
  float* cA1  = cv + 54528;
  float* cW2  = cv + 55040;
  float* cA2  = cv + 120576;
  int*   cPl  = (int*)(cv + 121088);

  bool ws_ok = (ws_size >= 8160 * sizeof(int));
  int* cSt = ws_ok ? (int*)d_ws : nullptr;

  ConvArgs a;
  a.src[0]  = d_in[2];        a.dst[0]  = cAx;  a.n[0]  = 8192;  a.kind[0]  = 0;
  a.src[1]  = d_in[3];        a.dst[1]  = cAy;  a.n[1]  = 8192;  a.kind[1]  = 0;
  a.src[2]  = d_in[4];        a.dst[2]  = cBx;  a.n[2]  = 8192;  a.kind[2]  = 0;
  a.src[3]  = d_in[5];        a.dst[3]  = cBy;  a.n[3]  = 8192;  a.kind[3]  = 0;
  a.src[4]  = d_in[base + 0]; a.dst[4]  = cEmb; a.n[4]  = 1120;  a.kind[4]  = 0;
  a.src[5]  = d_in[base + 1]; a.dst[5]  = cWc;  a.n[5]  = 64;    a.kind[5]  = 0;
  a.src[6]  = d_in[base + 2]; a.dst[6]  = cbc;  a.n[6]  = 32;    a.kind[6]  = 0;
  a.src[7]  = d_in[base + 3]; a.dst[7]  = cWm;  a.n[7]  = 4096;  a.kind[7]  = 0;
  a.src[8]  = d_in[base + 4]; a.dst[8]  = cbm;  a.n[8]  = 64;    a.kind[8]  = 0;
  a.src[9]  = d_in[base + 5]; a.dst[9]  = cW1;  a.n[9]  = 16384; a.kind[9]  = 0;
  a.src[10] = d_in[base + 6]; a.dst[10] = cA1;  a.n[10] = 512;   a.kind[10] = 0;
  a.src[11] = d_in[base + 7]; a.dst[11] = cW2;  a.n[11] = 65536; a.kind[11] = 0;
  a.src[12] = d_in[base + 8]; a.dst[12] = cA2;  a.n[12] = 512;   a.kind[12] = 0;
  a.src[13] = d_in[0];        a.dst[13] = cPl;  a.n[13] = 64;    a.kind[13] = 1;
  a.src[14] = d_in[1];        a.dst[14] = ws_ok ? (void*)cSt : (void*)cPl;
  a.n[14] = ws_ok ? 8160 : 0; a.kind[14] = 1;

  k_conv2<<<dim3(64, 15), 256, 0, stream>>>(a, (const unsigned*)d_in[base + 3],
                                            (const unsigned*)d_in[0]);

  k_feat2<<<BN / 64, 64, 0, stream>>>(cPl, cAx, cAy, cBx, cBy, cEmb, cWc, cbc, cWm, cbm, x);

  // ---- layer 1 ----
  k_gemm<<<dim3(BN / 64, 4), 256, 0, stream>>>(x, cW1, h, 64, cA1, ss, sd);
  k_attn_mfma2<1><<<B_ * 4 * (N_ / 128), 256, 0, stream>>>(h, ss, sd, x2);

  // ---- layer 2 ----
  k_gemm<<<dim3(BN / 64, 4), 256, 0, stream>>>(x2, cW2, h, 256, cA2, ss, sd);
  k_attn_mfma2<0><<<B_ * 4 * (N_ / 128), 256, 0, stream>>>(h, ss, sd, out_node);

  // ---- adjacency last (scratch lives in its output region) ----
  if (ws_ok) {
    k_adjf2<<<(ADJ_ELEMS / 4) / 256, 256, 0, stream>>>(cSt, out_adjf);
  } else {
    k_adjf<<<(ADJ_ELEMS / 4) / 256, 256, 0, stream>>>((const unsigned*)d_in[1], out_adjf);
  }

  if (mismatch >= 0) {
    float v = ldexpf(1024.f, mismatch);
    k_sentinel<<<1, 64, 0, stream>>>(out_node, v);
  }
}

// Round 13
// 638.818 us; speedup vs baseline: 3.2849x; 1.0141x over previous
//
#include <hip/hip_runtime.h>
#include <hip/hip_bf16.h>
#include <stdint.h>

static constexpr int B_  = 32;
static constexpr int E_  = 256;
static constexpr int N_  = 512;    // 2E
static constexpr int C_  = 256;    // H*F
static constexpr int BN  = B_ * N_;
static constexpr int NODE_ELEMS = B_ * N_ * C_;          // 4,194,304
static constexpr int ADJ_ELEMS  = B_ * 14 * N_ * N_;     // 117,440,512

#define LOG2E 1.44269504088896340736f

typedef __attribute__((ext_vector_type(8))) short v8bf;
typedef __attribute__((ext_vector_type(4))) float v4f;

__device__ __forceinline__ unsigned short f2bfbits(float f) {
  union { float f; unsigned u; } x; x.f = f;
  unsigned u = x.u;
  return (unsigned short)((u + 0x7FFFu + ((u >> 16) & 1u)) >> 16);
}

// ---------------- dtype-agnostic input conversion ----------------
// kind 0: float -> f32 ; kind 1: int -> i32 ; kind 2: float -> bf16 TRANSPOSED 256x256
struct ConvArgs {
  const void* src[15];
  void* dst[15];
  int n[15];
  int kind[15];
};

__global__ __launch_bounds__(256) void k_conv2(ConvArgs a, const unsigned* fprobe,
                                               const unsigned* iprobe) {
  __shared__ int fk_s, ik_s;
  int t = threadIdx.x;
  if (t == 0) {
    int c_even = 0, c_lo = 0;
    for (int k = 0; k < 32; ++k) {
      unsigned w = fprobe[2 * k];
      unsigned e32 = (w >> 23) & 0xFFu;
      unsigned elo = (w >> 7) & 0xFFu;
      if (e32 >= 105u && e32 <= 135u) ++c_even;
      if (elo >= 105u && elo <= 135u) ++c_lo;
    }
    fk_s = (c_even < 16) ? 2 : ((c_lo >= 16) ? 1 : 0);   // 2=f64, 1=bf16, 0=f32
    int hi0 = 0;
    for (int k = 0; k < 32; ++k) if (iprobe[2 * k + 1] == 0u) ++hi0;
    ik_s = (hi0 >= 30) ? 1 : 0;                          // 1=i64, 0=i32
  }
  __syncthreads();
  int fk = fk_s, ik = ik_s;
  int arr = blockIdx.y;
  int n = a.n[arr], kind = a.kind[arr];
  for (int idx = blockIdx.x * 256 + t; idx < n; idx += gridDim.x * 256) {
    if (kind == 1) {
      int v;
      if (ik == 1) v = (int)((const long long*)a.src[arr])[idx];
      else         v = ((const int*)a.src[arr])[idx];
      ((int*)a.dst[arr])[idx] = v;
    } else {
      float v;
      if (fk == 2) {
        v = (float)((const double*)a.src[arr])[idx];
      } else if (fk == 1) {
        unsigned short u = ((const unsigned short*)a.src[arr])[idx];
        union { unsigned u; float f; } c; c.u = (unsigned)u << 16; v = c.f;
      } else {
        v = ((const float*)a.src[arr])[idx];
      }
      if (kind == 0) {
        ((float*)a.dst[arr])[idx] = v;
      } else {           // kind 2: bf16, transposed [256][256]
        int kk = idx >> 8, cc = idx & 255;
        ((unsigned short*)a.dst[arr])[cc * 256 + kk] = f2bfbits(v);
      }
    }
  }
}

// ---------------- node features: one thread per node, 64-thr blocks ----------------
__global__ __launch_bounds__(64) void k_feat2(
    const int* __restrict__ player, const float* __restrict__ Ax, const float* __restrict__ Ay,
    const float* __restrict__ Bx, const float* __restrict__ By,
    const float* __restrict__ emb, const float* __restrict__ Wc, const float* __restrict__ bc,
    const float* __restrict__ Wm, const float* __restrict__ bm, float* __restrict__ x) {
  int id = blockIdx.x * 64 + threadIdx.x;   // b*512 + n
  if (id >= BN) return;
  int b = id >> 9, n = id & 511;
  int e = n >> 1, side = n & 1;
  float cx = side ? Bx[b * E_ + e] : Ax[b * E_ + e];
  float cy = side ? By[b * E_ + e] : Ay[b * E_ + e];
  int pid = player[b * 2 + side];
  float ct[32];
  for (int k = 0; k < 32; ++k)
    ct[k] = fmaxf(fmaf(cx, Wc[k], fmaf(cy, Wc[32 + k], bc[k])), 0.f);
  for (int o = 0; o < 64; ++o) {
    float acc = bm[o];
    for (int c = 0; c < 32; ++c) acc = fmaf(ct[c], Wm[c * 64 + o], acc);
    for (int c = 0; c < 32; ++c) acc = fmaf(emb[pid * 32 + c], Wm[(32 + c) * 64 + o], acc);
    x[(size_t)id * 64 + o] = acc;
  }
}

// ---------------- layer-1 tiled GEMM (f32) + fused GAT score epilogue ----------------
__global__ __launch_bounds__(256) void k_gemm(
    const float* __restrict__ x, const float* __restrict__ W, float* __restrict__ h, int K,
    const float* __restrict__ att, float* __restrict__ ssO, float* __restrict__ sdO) {
  __shared__ float xs[64 * 64];
  __shared__ float wt[64 * 64];
  int row0 = blockIdx.x * 64;
  int col0 = blockIdx.y * 64;
  int hd = blockIdx.y;
  int t = threadIdx.x;
  int tx = t & 15, ty = t >> 4;
  float acc[4][4] = {};
  for (int kt = 0; kt < K; kt += 64) {
    #pragma unroll
    for (int q = 0; q < 4; ++q) {
      int v = q * 256 + t;            // float4 chunk id 0..1023
      int r = v >> 4, c = (v & 15) * 4;
      *(float4*)&xs[r * 64 + c] = *(const float4*)&x[(size_t)(row0 + r) * K + kt + c];
      *(float4*)&wt[r * 64 + c] = *(const float4*)&W[(size_t)(kt + r) * C_ + col0 + c];
    }
    __syncthreads();
    #pragma unroll 4
    for (int k = 0; k < 64; ++k) {
      float xv[4];
      #pragma unroll
      for (int r = 0; r < 4; ++r) xv[r] = xs[(ty * 4 + r) * 64 + k];
      float4 wf = *(const float4*)&wt[k * 64 + tx * 4];
      #pragma unroll
      for (int r = 0; r < 4; ++r) {
        acc[r][0] = fmaf(xv[r], wf.x, acc[r][0]);
        acc[r][1] = fmaf(xv[r], wf.y, acc[r][1]);
        acc[r][2] = fmaf(xv[r], wf.z, acc[r][2]);
        acc[r][3] = fmaf(xv[r], wf.w, acc[r][3]);
      }
    }
    __syncthreads();
  }
  #pragma unroll
  for (int r = 0; r < 4; ++r) {
    int row = row0 + ty * 4 + r;
    float4 o = make_float4(acc[r][0], acc[r][1], acc[r][2], acc[r][3]);
    *(float4*)&h[(size_t)row * C_ + col0 + tx * 4] = o;
  }
  float attS[4], attD[4];
  #pragma unroll
  for (int c = 0; c < 4; ++c) {
    attS[c] = att[hd * 128 + tx * 4 + c];
    attD[c] = att[hd * 128 + 64 + tx * 4 + c];
  }
  #pragma unroll
  for (int r = 0; r < 4; ++r) {
    float p1 = acc[r][0] * attS[0] + acc[r][1] * attS[1] + acc[r][2] * attS[2] + acc[r][3] * attS[3];
    float p2 = acc[r][0] * attD[0] + acc[r][1] * attD[1] + acc[r][2] * attD[2] + acc[r][3] * attD[3];
    #pragma unroll
    for (int d = 8; d > 0; d >>= 1) {
      p1 += __shfl_xor(p1, d, 16);
      p2 += __shfl_xor(p2, d, 16);
    }
    if (tx == 0) {
      int row = row0 + ty * 4 + r;
      int bb = row >> 9, nn = row & 511;
      int idx = (bb * 4 + hd) * N_ + nn;
      ssO[idx] = p1; sdO[idx] = p2;
    }
  }
}

// ---------------- layer-2 MFMA GEMM (bf16 in, f32 out) + fused score epilogue ----------------
// xb: [BN][256] bf16 ; wt: W2T [col][k] bf16 (256x256). LDS-free.
__global__ __launch_bounds__(256) void k_gemm2_mfma(
    const unsigned short* __restrict__ xb, const unsigned short* __restrict__ wt,
    float* __restrict__ h, const float* __restrict__ att,
    float* __restrict__ ssO, float* __restrict__ sdO) {
  int row0 = blockIdx.x * 64;
  int col0 = blockIdx.y * 64;
  int hd = blockIdx.y;
  int t = threadIdx.x, w = t >> 6, l = t & 63;
  int lane16 = l & 15, quad = l >> 4;
  int arow = row0 + w * 16 + lane16;        // A m-row
  v4f acc[4] = {};
  #pragma unroll
  for (int ks = 0; ks < 8; ++ks) {
    int kb = ks * 32 + quad * 8;
    v8bf a = *(const v8bf*)&xb[(size_t)arow * 256 + kb];
    #pragma unroll
    for (int fs = 0; fs < 4; ++fs) {
      v8bf b = *(const v8bf*)&wt[(size_t)(col0 + fs * 16 + lane16) * 256 + kb];
      acc[fs] = __builtin_amdgcn_mfma_f32_16x16x32_bf16(a, b, acc[fs], 0, 0, 0);
    }
  }
  // C/D: col = col0 + fs*16 + lane16 ; row = row0 + w*16 + quad*4 + r
  float attS[4], attD[4];
  #pragma unroll
  for (int fs = 0; fs < 4; ++fs) {
    attS[fs] = att[hd * 128 + fs * 16 + lane16];
    attD[fs] = att[hd * 128 + 64 + fs * 16 + lane16];
  }
  #pragma unroll
  for (int r = 0; r < 4; ++r) {
    int row = row0 + w * 16 + quad * 4 + r;
    #pragma unroll
    for (int fs = 0; fs < 4; ++fs)
      h[(size_t)row * C_ + col0 + fs * 16 + lane16] = acc[fs][r];
    float p1 = acc[0][r] * attS[0] + acc[1][r] * attS[1] + acc[2][r] * attS[2] + acc[3][r] * attS[3];
    float p2 = acc[0][r] * attD[0] + acc[1][r] * attD[1] + acc[2][r] * attD[2] + acc[3][r] * attD[3];
    #pragma unroll
    for (int d = 8; d > 0; d >>= 1) {
      p1 += __shfl_xor(p1, d, 16);
      p2 += __shfl_xor(p2, d, 16);
    }
    if (lane16 == 0) {
      int bb = row >> 9, nn = row & 511;
      int idx = (bb * 4 + hd) * N_ + nn;
      ssO[idx] = p1; sdO[idx] = p2;
    }
  }
}

// ---------------- MFMA attention (self-contained softmax stats) ----------------
// RELU=1: out = bf16 x2b (relu) ; RELU=0: out = f32 node embedding.
template <int RELU>
__global__ __launch_bounds__(256) void k_attn_mfma2(
    const float* __restrict__ h, const float* __restrict__ ss, const float* __restrict__ sd,
    void* __restrict__ outp) {
  __shared__ unsigned short hs[64 * 72];   // hs[f*72 + j], bf16
  __shared__ float sdl[512];
  __shared__ float red[4];
  __shared__ float ls[4][32];
  int blk = blockIdx.x;
  int it = blk & 3, hd = (blk >> 2) & 3, b = blk >> 4;
  int i0 = it * 128, bh = b * 4 + hd;
  int t = threadIdx.x, w = t >> 6, l = t & 63;
  int lane16 = l & 15, quad = l >> 4;
  float v0 = sd[(size_t)bh * N_ + t];
  float v1 = sd[(size_t)bh * N_ + 256 + t];
  sdl[t] = v0; sdl[256 + t] = v1;
  float mx = fmaxf(v0, v1);
  #pragma unroll
  for (int d = 32; d > 0; d >>= 1) mx = fmaxf(mx, __shfl_xor(mx, d, 64));
  if (l == 0) red[w] = mx;
  __syncthreads();
  mx = fmaxf(fmaxf(red[0], red[1]), fmaxf(red[2], red[3]));
  float ss_s[2], m2_s[2], lsum[2] = {0.f, 0.f};
  #pragma unroll
  for (int s = 0; s < 2; ++s) {
    int i = i0 + w * 32 + s * 16 + lane16;
    ss_s[s] = ss[(size_t)bh * N_ + i];
    float sv = ss_s[s] + mx;
    m2_s[s] = fmaxf(sv, 0.2f * sv) * LOG2E;   // leaky monotone -> row-max bound
  }
  v4f acc[2][4] = {};
  for (int jt = 0; jt < 8; ++jt) {
    int j0 = jt * 64;
    #pragma unroll
    for (int q = 0; q < 4; ++q) {
      int v = q * 256 + t;
      int j = v >> 4, f0 = (v & 15) * 4;
      float4 hv = *(const float4*)&h[(size_t)(b * N_ + j0 + j) * C_ + hd * 64 + f0];
      hs[(f0 + 0) * 72 + j] = f2bfbits(hv.x);
      hs[(f0 + 1) * 72 + j] = f2bfbits(hv.y);
      hs[(f0 + 2) * 72 + j] = f2bfbits(hv.z);
      hs[(f0 + 3) * 72 + j] = f2bfbits(hv.w);
    }
    __syncthreads();
    #pragma unroll
    for (int ks = 0; ks < 2; ++ks) {
      int kb = ks * 32;
      v8bf afr[2];
      #pragma unroll
      for (int s = 0; s < 2; ++s) {
        int i = i0 + w * 32 + s * 16 + lane16;
        #pragma unroll
        for (int q = 0; q < 8; ++q) {
          int j = j0 + kb + quad * 8 + q;
          float sv = ss_s[s] + sdl[j];
          float sc = fmaxf(sv, 0.2f * sv);
          float p = exp2f(fmaf(sc, LOG2E, -m2_s[s]));
          if (i == j) p = 0.f;
          lsum[s] += p;
          afr[s][q] = (short)f2bfbits(p);
        }
      }
      #pragma unroll
      for (int fs = 0; fs < 4; ++fs) {
        v8bf bfr = *(const v8bf*)&hs[(fs * 16 + lane16) * 72 + kb + quad * 8];
        acc[0][fs] = __builtin_amdgcn_mfma_f32_16x16x32_bf16(afr[0], bfr, acc[0][fs], 0, 0, 0);
        acc[1][fs] = __builtin_amdgcn_mfma_f32_16x16x32_bf16(afr[1], bfr, acc[1][fs], 0, 0, 0);
      }
    }
    __syncthreads();
  }
  #pragma unroll
  for (int s = 0; s < 2; ++s) {
    lsum[s] += __shfl_xor(lsum[s], 16, 64);
    lsum[s] += __shfl_xor(lsum[s], 32, 64);
    if (quad == 0) ls[w][s * 16 + lane16] = lsum[s];
  }
  __syncthreads();
  #pragma unroll
  for (int s = 0; s < 2; ++s) {
    #pragma unroll
    for (int r = 0; r < 4; ++r) {
      int i = i0 + w * 32 + s * 16 + quad * 4 + r;
      float scale = 1.f / ls[w][s * 16 + quad * 4 + r];
      #pragma unroll
      for (int fs = 0; fs < 4; ++fs) {
        int f = fs * 16 + lane16;
        float vv = acc[s][fs][r] * scale;
        size_t o = (size_t)(b * N_ + i) * C_ + hd * 64 + f;
        if constexpr (RELU) {
          ((unsigned short*)outp)[o] = f2bfbits(fmaxf(vv, 0.f));
        } else {
          ((float*)outp)[o] = vv;
        }
      }
    }
  }
}

// ---------------- adjacency v2: pure analytic fill from converted i32 st ----------------
__global__ __launch_bounds__(256) void k_adjf2(
    const int* __restrict__ st, float* __restrict__ adj) {
  int chunk = blockIdx.x * 256 + threadIdx.x;   // float4 id
  int j0 = (chunk & 127) << 2;
  int rowid = chunk >> 7;
  int i = rowid & 511;
  int plane = rowid >> 9;                        // b*14 + r
  int r = plane % 14;
  int b = plane / 14;
  float vals[4];
  #pragma unroll
  for (int q = 0; q < 4; ++q) {
    int j = j0 + q;
    int d = j - i;
    int ad = d < 0 ? -d : d;
    int mn = d < 0 ? j : i;
    int m4 = mn & 3;
    float v = 0.f;
    if (r == 13) {
      bool excl = (d == 0) || (ad == 2) || (ad == 3 && m4 == 0) || (ad == 1 && m4 == 3);
      v = excl ? 0.f : 1.f;
    } else if (r == 11) {
      v = (ad == 2 && (m4 == 0 || m4 == 3)) ? 1.f : 0.f;
    } else if (r == 12) {
      v = (ad == 2 && (m4 == 1 || m4 == 2)) ? 1.f : 0.f;
    } else {
      bool sp = (ad == 3 && m4 == 0) || (ad == 1 && m4 == 3);
      if (sp) v = (st[b * 255 + (mn >> 1)] == r) ? 1.f : 0.f;
    }
    vals[q] = v;
  }
  *(float4*)&adj[(size_t)chunk * 4] = make_float4(vals[0], vals[1], vals[2], vals[3]);
}

// ---------------- adjacency fallback: raw input + per-block sniff ----------------
__global__ __launch_bounds__(256) void k_adjf(
    const unsigned* __restrict__ st_raw, float* __restrict__ adj) {
  __shared__ int i64_s;
  if (threadIdx.x == 0) {
    int hi0 = 0;
    for (int k = 0; k < 32; ++k) if (st_raw[2 * k + 1] == 0u) ++hi0;
    i64_s = (hi0 >= 30) ? 1 : 0;
  }
  __syncthreads();
  int is64 = i64_s;
  int chunk = blockIdx.x * 256 + threadIdx.x;
  int j0 = (chunk & 127) << 2;
  int rowid = chunk >> 7;
  int i = rowid & 511;
  int plane = rowid >> 9;
  int r = plane % 14;
  int b = plane / 14;
  float vals[4];
  #pragma unroll
  for (int q = 0; q < 4; ++q) {
    int j = j0 + q;
    int d = j - i;
    int ad = d < 0 ? -d : d;
    int mn = d < 0 ? j : i;
    int m4 = mn & 3;
    float v = 0.f;
    if (r == 13) {
      bool excl = (d == 0) || (ad == 2) || (ad == 3 && m4 == 0) || (ad == 1 && m4 == 3);
      v = excl ? 0.f : 1.f;
    } else if (r == 11) {
      v = (ad == 2 && (m4 == 0 || m4 == 3)) ? 1.f : 0.f;
    } else if (r == 12) {
      v = (ad == 2 && (m4 == 1 || m4 == 2)) ? 1.f : 0.f;
    } else {
      bool sp = (ad == 3 && m4 == 0) || (ad == 1 && m4 == 3);
      if (sp) {
        int e = b * 255 + (mn >> 1);
        int stv = is64 ? (int)st_raw[2 * e] : (int)st_raw[e];
        v = (stv == r) ? 1.f : 0.f;
      }
    }
    vals[q] = v;
  }
  *(float4*)&adj[(size_t)chunk * 4] = make_float4(vals[0], vals[1], vals[2], vals[3]);
}

// ---------------- sentinel ----------------
__global__ void k_sentinel(float* out, float v) {
  if (threadIdx.x == 0 && blockIdx.x == 0) out[0] = v;
}

extern "C" void kernel_launch(void* const* d_in, const int* in_sizes, int n_in,
                              void* d_out, int out_size, void* d_ws, size_t ws_size,
                              hipStream_t stream) {
  static const int expA[16] = {64,8160,8192,8192,8192,8192,1,1120,64,32,4096,64,16384,512,65536,512};
  static const int expB[15] = {64,8160,8192,8192,8192,8192,1120,64,32,4096,64,16384,512,65536,512};
  int mismatch = -1;
  int base = 7;
  if (n_in == 16) {
    base = 7;
    for (int i = 0; i < 16; ++i) if (in_sizes[i] != expA[i]) { mismatch = i; break; }
  } else if (n_in == 15) {
    base = 6;
    for (int i = 0; i < 15; ++i) if (in_sizes[i] != expB[i]) { mismatch = i; break; }
  } else {
    mismatch = 17;
  }
  if (mismatch < 0 && out_size != NODE_ELEMS + ADJ_ELEMS) mismatch = 16;

  float* out_node = (float*)d_out;                 // f32 output
  float* out_adjf = out_node + NODE_ELEMS;

  // Scratch carved from the f32 adj output region (470 MB); adj written last.
  char* scr = (char*)out_adjf;
  float* x  = (float*)(scr);                       //  4 MB
  float* h  = (float*)(scr + (size_t)( 4u << 20)); // 16 MB
  unsigned short* x2b = (unsigned short*)(scr + (size_t)(24u << 20)); // 8 MB bf16
  float* ss = (float*)(scr + (size_t)(44u << 20)); // 256 KB
  float* sd = (float*)(scr + (size_t)(45u << 20)); // 256 KB
  float* cv = (float*)(scr + (size_t)(48u << 20)); // converted inputs

  float* cAx  = cv + 0;
  float* cAy  = cv + 8192;
  float* cBx  = cv + 16384;
  float* cBy  = cv + 24576;
  float* cEmb = cv + 32768;
  float* cWc  = cv + 33888;
  float* cbc  = cv + 33952;
  float* cWm  = cv + 33984;
  float* cbm  = cv + 38080;
  float* cW1  = cv + 38144;
  float* cA1  = cv + 54528;
  unsigned short* cW2T = (unsigned short*)(cv + 55040);  // 128 KB bf16 transposed
  float* cA2  = cv + 120576;
  int*   cPl  = (int*)(cv + 121088);

  bool ws_ok = (ws_size >= 8160 * sizeof(int));
  int* cSt = ws_ok ? (int*)d_ws : nullptr;

  ConvArgs a;
  a.src[0]  = d_in[2];        a.dst[0]  = cAx;  a.n[0]  = 8192;  a.kind[0]  = 0;
  a.src[1]  = d_in[3];        a.dst[1]  = cAy;  a.n[1]  = 8192;  a.kind[1]  = 0;
  a.src[2]  = d_in[4];        a.dst[2]  = cBx;  a.n[2]  = 8192;  a.kind[2]  = 0;
  a.src[3]  = d_in[5];        a.dst[3]  = cBy;  a.n[3]  = 8192;  a.kind[3]  = 0;
  a.src[4]  = d_in[base + 0]; a.dst[4]  = cEmb; a.n[4]  = 1120;  a.kind[4]  = 0;
  a.src[5]  = d_in[base + 1]; a.dst[5]  = cWc;  a.n[5]  = 64;    a.kind[5]  = 0;
  a.src[6]  = d_in[base + 2]; a.dst[6]  = cbc;  a.n[6]  = 32;    a.kind[6]  = 0;
  a.src[7]  = d_in[base + 3]; a.dst[7]  = cWm;  a.n[7]  = 4096;  a.kind[7]  = 0;
  a.src[8]  = d_in[base + 4]; a.dst[8]  = cbm;  a.n[8]  = 64;    a.kind[8]  = 0;
  a.src[9]  = d_in[base + 5]; a.dst[9]  = cW1;  a.n[9]  = 16384; a.kind[9]  = 0;
  a.src[10] = d_in[base + 6]; a.dst[10] = cA1;  a.n[10] = 512;   a.kind[10] = 0;
  a.src[11] = d_in[base + 7]; a.dst[11] = cW2T; a.n[11] = 65536; a.kind[11] = 2;
  a.src[12] = d_in[base + 8]; a.dst[12] = cA2;  a.n[12] = 512;   a.kind[12] = 0;
  a.src[13] = d_in[0];        a.dst[13] = cPl;  a.n[13] = 64;    a.kind[13] = 1;
  a.src[14] = d_in[1];        a.dst[14] = ws_ok ? (void*)cSt : (void*)cPl;
  a.n[14] = ws_ok ? 8160 : 0; a.kind[14] = 1;

  k_conv2<<<dim3(64, 15), 256, 0, stream>>>(a, (const unsigned*)d_in[base + 3],
                                            (const unsigned*)d_in[0]);

  k_feat2<<<BN / 64, 64, 0, stream>>>(cPl, cAx, cAy, cBx, cBy, cEmb, cWc, cbc, cWm, cbm, x);

  // ---- layer 1 ----
  k_gemm<<<dim3(BN / 64, 4), 256, 0, stream>>>(x, cW1, h, 64, cA1, ss, sd);
  k_attn_mfma2<1><<<B_ * 4 * (N_ / 128), 256, 0, stream>>>(h, ss, sd, x2b);

  // ---- layer 2 ----
  k_gemm2_mfma<<<dim3(BN / 64, 4), 256, 0, stream>>>(x2b, cW2T, h, cA2, ss, sd);
  k_attn_mfma2<0><<<B_ * 4 * (N_ / 128), 256, 0, stream>>>(h, ss, sd, out_node);

  // ---- adjacency last (scratch lives in its output region) ----
  if (ws_ok) {
    k_adjf2<<<(ADJ_ELEMS / 4) / 256, 256, 0, stream>>>(cSt, out_adjf);
  } else {
    k_adjf<<<(ADJ_ELEMS / 4) / 256, 256, 0, stream>>>((const unsigned*)d_in[1], out_adjf);
  }

  if (mismatch >= 0) {
    float v = ldexpf(1024.f, mismatch);
    k_sentinel<<<1, 64, 0, stream>>>(out_node, v);
  }
}

// Round 14
// 629.621 us; speedup vs baseline: 3.3328x; 1.0146x over previous
//
#include <hip/hip_runtime.h>
#include <hip/hip_bf16.h>
#include <stdint.h>

static constexpr int B_  = 32;
static constexpr int E_  = 256;
static constexpr int N_  = 512;    // 2E
static constexpr int C_  = 256;    // H*F
static constexpr int BN  = B_ * N_;
static constexpr int NODE_ELEMS = B_ * N_ * C_;          // 4,194,304
static constexpr int ADJ_ELEMS  = B_ * 14 * N_ * N_;     // 117,440,512

#define LOG2E 1.44269504088896340736f

typedef __attribute__((ext_vector_type(8))) short v8bf;
typedef __attribute__((ext_vector_type(4))) float v4f;

__device__ __forceinline__ unsigned short f2bfbits(float f) {
  union { float f; unsigned u; } x; x.f = f;
  unsigned u = x.u;
  return (unsigned short)((u + 0x7FFFu + ((u >> 16) & 1u)) >> 16);
}

// ---------------- dtype-agnostic input conversion ----------------
// kind 0: float -> f32 ; kind 1: int -> i32 ; kind 2: float -> bf16 TRANSPOSED 256x256
struct ConvArgs {
  const void* src[15];
  void* dst[15];
  int n[15];
  int kind[15];
};

__global__ __launch_bounds__(256) void k_conv2(ConvArgs a, const unsigned* fprobe,
                                               const unsigned* iprobe) {
  __shared__ int fk_s, ik_s;
  int t = threadIdx.x;
  if (t == 0) {
    int c_even = 0, c_lo = 0;
    for (int k = 0; k < 32; ++k) {
      unsigned w = fprobe[2 * k];
      unsigned e32 = (w >> 23) & 0xFFu;
      unsigned elo = (w >> 7) & 0xFFu;
      if (e32 >= 105u && e32 <= 135u) ++c_even;
      if (elo >= 105u && elo <= 135u) ++c_lo;
    }
    fk_s = (c_even < 16) ? 2 : ((c_lo >= 16) ? 1 : 0);   // 2=f64, 1=bf16, 0=f32
    int hi0 = 0;
    for (int k = 0; k < 32; ++k) if (iprobe[2 * k + 1] == 0u) ++hi0;
    ik_s = (hi0 >= 30) ? 1 : 0;                          // 1=i64, 0=i32
  }
  __syncthreads();
  int fk = fk_s, ik = ik_s;
  int arr = blockIdx.y;
  int n = a.n[arr], kind = a.kind[arr];
  for (int idx = blockIdx.x * 256 + t; idx < n; idx += gridDim.x * 256) {
    if (kind == 1) {
      int v;
      if (ik == 1) v = (int)((const long long*)a.src[arr])[idx];
      else         v = ((const int*)a.src[arr])[idx];
      ((int*)a.dst[arr])[idx] = v;
    } else {
      float v;
      if (fk == 2) {
        v = (float)((const double*)a.src[arr])[idx];
      } else if (fk == 1) {
        unsigned short u = ((const unsigned short*)a.src[arr])[idx];
        union { unsigned u; float f; } c; c.u = (unsigned)u << 16; v = c.f;
      } else {
        v = ((const float*)a.src[arr])[idx];
      }
      if (kind == 0) {
        ((float*)a.dst[arr])[idx] = v;
      } else {           // kind 2: bf16, transposed [256][256]
        int kk = idx >> 8, cc = idx & 255;
        ((unsigned short*)a.dst[arr])[cc * 256 + kk] = f2bfbits(v);
      }
    }
  }
}

// ---------------- node features v3: one WAVE per node ----------------
__global__ __launch_bounds__(64) void k_feat3(
    const int* __restrict__ player, const float* __restrict__ Ax, const float* __restrict__ Ay,
    const float* __restrict__ Bx, const float* __restrict__ By,
    const float* __restrict__ emb, const float* __restrict__ Wc, const float* __restrict__ bc,
    const float* __restrict__ Wm, const float* __restrict__ bm, float* __restrict__ x) {
  int id = blockIdx.x;                  // b*512 + n
  int b = id >> 9, n = id & 511;
  int e = n >> 1, side = n & 1;
  int t = threadIdx.x;
  __shared__ float feat[64];
  float v;
  if (t < 32) {
    float cx = side ? Bx[b * E_ + e] : Ax[b * E_ + e];
    float cy = side ? By[b * E_ + e] : Ay[b * E_ + e];
    v = fmaxf(fmaf(cx, Wc[t], fmaf(cy, Wc[32 + t], bc[t])), 0.f);
  } else {
    int pid = player[b * 2 + side];
    v = emb[pid * 32 + (t - 32)];
  }
  feat[t] = v;
  __syncthreads();
  float acc = bm[t];
  #pragma unroll 8
  for (int c = 0; c < 64; ++c) acc = fmaf(feat[c], Wm[c * 64 + t], acc);
  x[(size_t)id * 64 + t] = acc;
}

// ---------------- layer-1 tiled GEMM (f32) + fused GAT score epilogue ----------------
__global__ __launch_bounds__(256) void k_gemm(
    const float* __restrict__ x, const float* __restrict__ W, float* __restrict__ h, int K,
    const float* __restrict__ att, float* __restrict__ ssO, float* __restrict__ sdO) {
  __shared__ float xs[64 * 64];
  __shared__ float wt[64 * 64];
  int row0 = blockIdx.x * 64;
  int col0 = blockIdx.y * 64;
  int hd = blockIdx.y;
  int t = threadIdx.x;
  int tx = t & 15, ty = t >> 4;
  float acc[4][4] = {};
  for (int kt = 0; kt < K; kt += 64) {
    #pragma unroll
    for (int q = 0; q < 4; ++q) {
      int v = q * 256 + t;            // float4 chunk id 0..1023
      int r = v >> 4, c = (v & 15) * 4;
      *(float4*)&xs[r * 64 + c] = *(const float4*)&x[(size_t)(row0 + r) * K + kt + c];
      *(float4*)&wt[r * 64 + c] = *(const float4*)&W[(size_t)(kt + r) * C_ + col0 + c];
    }
    __syncthreads();
    #pragma unroll 4
    for (int k = 0; k < 64; ++k) {
      float xv[4];
      #pragma unroll
      for (int r = 0; r < 4; ++r) xv[r] = xs[(ty * 4 + r) * 64 + k];
      float4 wf = *(const float4*)&wt[k * 64 + tx * 4];
      #pragma unroll
      for (int r = 0; r < 4; ++r) {
        acc[r][0] = fmaf(xv[r], wf.x, acc[r][0]);
        acc[r][1] = fmaf(xv[r], wf.y, acc[r][1]);
        acc[r][2] = fmaf(xv[r], wf.z, acc[r][2]);
        acc[r][3] = fmaf(xv[r], wf.w, acc[r][3]);
      }
    }
    __syncthreads();
  }
  #pragma unroll
  for (int r = 0; r < 4; ++r) {
    int row = row0 + ty * 4 + r;
    float4 o = make_float4(acc[r][0], acc[r][1], acc[r][2], acc[r][3]);
    *(float4*)&h[(size_t)row * C_ + col0 + tx * 4] = o;
  }
  float attS[4], attD[4];
  #pragma unroll
  for (int c = 0; c < 4; ++c) {
    attS[c] = att[hd * 128 + tx * 4 + c];
    attD[c] = att[hd * 128 + 64 + tx * 4 + c];
  }
  #pragma unroll
  for (int r = 0; r < 4; ++r) {
    float p1 = acc[r][0] * attS[0] + acc[r][1] * attS[1] + acc[r][2] * attS[2] + acc[r][3] * attS[3];
    float p2 = acc[r][0] * attD[0] + acc[r][1] * attD[1] + acc[r][2] * attD[2] + acc[r][3] * attD[3];
    #pragma unroll
    for (int d = 8; d > 0; d >>= 1) {
      p1 += __shfl_xor(p1, d, 16);
      p2 += __shfl_xor(p2, d, 16);
    }
    if (tx == 0) {
      int row = row0 + ty * 4 + r;
      int bb = row >> 9, nn = row & 511;
      int idx = (bb * 4 + hd) * N_ + nn;
      ssO[idx] = p1; sdO[idx] = p2;
    }
  }
}

// ---------------- layer-2 MFMA GEMM (bf16 in, f32 out) + fused score epilogue ----------------
__global__ __launch_bounds__(256) void k_gemm2_mfma(
    const unsigned short* __restrict__ xb, const unsigned short* __restrict__ wt,
    float* __restrict__ h, const float* __restrict__ att,
    float* __restrict__ ssO, float* __restrict__ sdO) {
  int row0 = blockIdx.x * 64;
  int col0 = blockIdx.y * 64;
  int hd = blockIdx.y;
  int t = threadIdx.x, w = t >> 6, l = t & 63;
  int lane16 = l & 15, quad = l >> 4;
  int arow = row0 + w * 16 + lane16;        // A m-row
  v4f acc[4] = {};
  #pragma unroll
  for (int ks = 0; ks < 8; ++ks) {
    int kb = ks * 32 + quad * 8;
    v8bf a = *(const v8bf*)&xb[(size_t)arow * 256 + kb];
    #pragma unroll
    for (int fs = 0; fs < 4; ++fs) {
      v8bf b = *(const v8bf*)&wt[(size_t)(col0 + fs * 16 + lane16) * 256 + kb];
      acc[fs] = __builtin_amdgcn_mfma_f32_16x16x32_bf16(a, b, acc[fs], 0, 0, 0);
    }
  }
  float attS[4], attD[4];
  #pragma unroll
  for (int fs = 0; fs < 4; ++fs) {
    attS[fs] = att[hd * 128 + fs * 16 + lane16];
    attD[fs] = att[hd * 128 + 64 + fs * 16 + lane16];
  }
  #pragma unroll
  for (int r = 0; r < 4; ++r) {
    int row = row0 + w * 16 + quad * 4 + r;
    #pragma unroll
    for (int fs = 0; fs < 4; ++fs)
      h[(size_t)row * C_ + col0 + fs * 16 + lane16] = acc[fs][r];
    float p1 = acc[0][r] * attS[0] + acc[1][r] * attS[1] + acc[2][r] * attS[2] + acc[3][r] * attS[3];
    float p2 = acc[0][r] * attD[0] + acc[1][r] * attD[1] + acc[2][r] * attD[2] + acc[3][r] * attD[3];
    #pragma unroll
    for (int d = 8; d > 0; d >>= 1) {
      p1 += __shfl_xor(p1, d, 16);
      p2 += __shfl_xor(p2, d, 16);
    }
    if (lane16 == 0) {
      int bb = row >> 9, nn = row & 511;
      int idx = (bb * 4 + hd) * N_ + nn;
      ssO[idx] = p1; sdO[idx] = p2;
    }
  }
}

// ---------------- MFMA attention v3: i-tile 64, 1024 blocks ----------------
// RELU=1: out = bf16 x2b (relu) ; RELU=0: out = f32 node embedding.
template <int RELU>
__global__ __launch_bounds__(256) void k_attn_mfma3(
    const float* __restrict__ h, const float* __restrict__ ss, const float* __restrict__ sd,
    void* __restrict__ outp) {
  __shared__ unsigned short hs[64 * 72];   // hs[f*72 + j], bf16
  __shared__ float sdl[512];
  __shared__ float red[4];
  __shared__ float ls[4][16];
  int blk = blockIdx.x;
  int it = blk & 7, hd = (blk >> 3) & 3, b = blk >> 5;
  int i0 = it * 64, bh = b * 4 + hd;
  int t = threadIdx.x, w = t >> 6, l = t & 63;
  int lane16 = l & 15, quad = l >> 4;
  float v0 = sd[(size_t)bh * N_ + t];
  float v1 = sd[(size_t)bh * N_ + 256 + t];
  sdl[t] = v0; sdl[256 + t] = v1;
  float mx = fmaxf(v0, v1);
  #pragma unroll
  for (int d = 32; d > 0; d >>= 1) mx = fmaxf(mx, __shfl_xor(mx, d, 64));
  if (l == 0) red[w] = mx;
  __syncthreads();
  mx = fmaxf(fmaxf(red[0], red[1]), fmaxf(red[2], red[3]));
  int iw = i0 + w * 16 + lane16;           // this lane's i
  float ss_s = ss[(size_t)bh * N_ + iw];
  float sv0 = ss_s + mx;
  float m2_s = fmaxf(sv0, 0.2f * sv0) * LOG2E;  // leaky monotone -> row-max bound
  float lsum = 0.f;
  v4f acc[4] = {};
  for (int jt = 0; jt < 8; ++jt) {
    int j0 = jt * 64;
    #pragma unroll
    for (int q = 0; q < 4; ++q) {
      int v = q * 256 + t;
      int j = v >> 4, f0 = (v & 15) * 4;
      float4 hv = *(const float4*)&h[(size_t)(b * N_ + j0 + j) * C_ + hd * 64 + f0];
      hs[(f0 + 0) * 72 + j] = f2bfbits(hv.x);
      hs[(f0 + 1) * 72 + j] = f2bfbits(hv.y);
      hs[(f0 + 2) * 72 + j] = f2bfbits(hv.z);
      hs[(f0 + 3) * 72 + j] = f2bfbits(hv.w);
    }
    __syncthreads();
    #pragma unroll
    for (int ks = 0; ks < 2; ++ks) {
      int kb = ks * 32;
      v8bf afr;
      #pragma unroll
      for (int q = 0; q < 8; ++q) {
        int j = j0 + kb + quad * 8 + q;
        float sv = ss_s + sdl[j];
        float sc = fmaxf(sv, 0.2f * sv);
        float p = exp2f(fmaf(sc, LOG2E, -m2_s));
        if (iw == j) p = 0.f;
        lsum += p;
        afr[q] = (short)f2bfbits(p);
      }
      #pragma unroll
      for (int fs = 0; fs < 4; ++fs) {
        v8bf bfr = *(const v8bf*)&hs[(fs * 16 + lane16) * 72 + kb + quad * 8];
        acc[fs] = __builtin_amdgcn_mfma_f32_16x16x32_bf16(afr, bfr, acc[fs], 0, 0, 0);
      }
    }
    __syncthreads();
  }
  // cross-quad reduce of row sums; transpose via LDS
  lsum += __shfl_xor(lsum, 16, 64);
  lsum += __shfl_xor(lsum, 32, 64);
  if (quad == 0) ls[w][lane16] = lsum;
  __syncthreads();
  // epilogue: C/D layout col = lane16 (f), row = quad*4 + reg (i)
  #pragma unroll
  for (int r = 0; r < 4; ++r) {
    int i = i0 + w * 16 + quad * 4 + r;
    float scale = 1.f / ls[w][quad * 4 + r];
    #pragma unroll
    for (int fs = 0; fs < 4; ++fs) {
      int f = fs * 16 + lane16;
      float vv = acc[fs][r] * scale;
      size_t o = (size_t)(b * N_ + i) * C_ + hd * 64 + f;
      if constexpr (RELU) {
        ((unsigned short*)outp)[o] = f2bfbits(fmaxf(vv, 0.f));
      } else {
        ((float*)outp)[o] = vv;
      }
    }
  }
}

// ---------------- adjacency v2: pure analytic fill from converted i32 st ----------------
__global__ __launch_bounds__(256) void k_adjf2(
    const int* __restrict__ st, float* __restrict__ adj) {
  int chunk = blockIdx.x * 256 + threadIdx.x;   // float4 id
  int j0 = (chunk & 127) << 2;
  int rowid = chunk >> 7;
  int i = rowid & 511;
  int plane = rowid >> 9;                        // b*14 + r
  int r = plane % 14;
  int b = plane / 14;
  float vals[4];
  #pragma unroll
  for (int q = 0; q < 4; ++q) {
    int j = j0 + q;
    int d = j - i;
    int ad = d < 0 ? -d : d;
    int mn = d < 0 ? j : i;
    int m4 = mn & 3;
    float v = 0.f;
    if (r == 13) {
      bool excl = (d == 0) || (ad == 2) || (ad == 3 && m4 == 0) || (ad == 1 && m4 == 3);
      v = excl ? 0.f : 1.f;
    } else if (r == 11) {
      v = (ad == 2 && (m4 == 0 || m4 == 3)) ? 1.f : 0.f;
    } else if (r == 12) {
      v = (ad == 2 && (m4 == 1 || m4 == 2)) ? 1.f : 0.f;
    } else {
      bool sp = (ad == 3 && m4 == 0) || (ad == 1 && m4 == 3);
      if (sp) v = (st[b * 255 + (mn >> 1)] == r) ? 1.f : 0.f;
    }
    vals[q] = v;
  }
  *(float4*)&adj[(size_t)chunk * 4] = make_float4(vals[0], vals[1], vals[2], vals[3]);
}

// ---------------- adjacency fallback: raw input + per-block sniff ----------------
__global__ __launch_bounds__(256) void k_adjf(
    const unsigned* __restrict__ st_raw, float* __restrict__ adj) {
  __shared__ int i64_s;
  if (threadIdx.x == 0) {
    int hi0 = 0;
    for (int k = 0; k < 32; ++k) if (st_raw[2 * k + 1] == 0u) ++hi0;
    i64_s = (hi0 >= 30) ? 1 : 0;
  }
  __syncthreads();
  int is64 = i64_s;
  int chunk = blockIdx.x * 256 + threadIdx.x;
  int j0 = (chunk & 127) << 2;
  int rowid = chunk >> 7;
  int i = rowid & 511;
  int plane = rowid >> 9;
  int r = plane % 14;
  int b = plane / 14;
  float vals[4];
  #pragma unroll
  for (int q = 0; q < 4; ++q) {
    int j = j0 + q;
    int d = j - i;
    int ad = d < 0 ? -d : d;
    int mn = d < 0 ? j : i;
    int m4 = mn & 3;
    float v = 0.f;
    if (r == 13) {
      bool excl = (d == 0) || (ad == 2) || (ad == 3 && m4 == 0) || (ad == 1 && m4 == 3);
      v = excl ? 0.f : 1.f;
    } else if (r == 11) {
      v = (ad == 2 && (m4 == 0 || m4 == 3)) ? 1.f : 0.f;
    } else if (r == 12) {
      v = (ad == 2 && (m4 == 1 || m4 == 2)) ? 1.f : 0.f;
    } else {
      bool sp = (ad == 3 && m4 == 0) || (ad == 1 && m4 == 3);
      if (sp) {
        int e = b * 255 + (mn >> 1);
        int stv = is64 ? (int)st_raw[2 * e] : (int)st_raw[e];
        v = (stv == r) ? 1.f : 0.f;
      }
    }
    vals[q] = v;
  }
  *(float4*)&adj[(size_t)chunk * 4] = make_float4(vals[0], vals[1], vals[2], vals[3]);
}

// ---------------- sentinel ----------------
__global__ void k_sentinel(float* out, float v) {
  if (threadIdx.x == 0 && blockIdx.x == 0) out[0] = v;
}

extern "C" void kernel_launch(void* const* d_in, const int* in_sizes, int n_in,
                              void* d_out, int out_size, void* d_ws, size_t ws_size,
                              hipStream_t stream) {
  static const int expA[16] = {64,8160,8192,8192,8192,8192,1,1120,64,32,4096,64,16384,512,65536,512};
  static const int expB[15] = {64,8160,8192,8192,8192,8192,1120,64,32,4096,64,16384,512,65536,512};
  int mismatch = -1;
  int base = 7;
  if (n_in == 16) {
    base = 7;
    for (int i = 0; i < 16; ++i) if (in_sizes[i] != expA[i]) { mismatch = i; break; }
  } else if (n_in == 15) {
    base = 6;
    for (int i = 0; i < 15; ++i) if (in_sizes[i] != expB[i]) { mismatch = i; break; }
  } else {
    mismatch = 17;
  }
  if (mismatch < 0 && out_size != NODE_ELEMS + ADJ_ELEMS) mismatch = 16;

  float* out_node = (float*)d_out;                 // f32 output
  float* out_adjf = out_node + NODE_ELEMS;

  // Scratch carved from the f32 adj output region (470 MB); adj written last.
  char* scr = (char*)out_adjf;
  float* x  = (float*)(scr);                       //  4 MB
  float* h  = (float*)(scr + (size_t)( 4u << 20)); // 16 MB
  unsigned short* x2b = (unsigned short*)(scr + (size_t)(24u << 20)); // 8 MB bf16
  float* ss = (float*)(scr + (size_t)(44u << 20)); // 256 KB
  float* sd = (float*)(scr + (size_t)(45u << 20)); // 256 KB
  float* cv = (float*)(scr + (size_t)(48u << 20)); // converted inputs

  float* cAx  = cv + 0;
  float* cAy  = cv + 8192;
  float* cBx  = cv + 16384;
  float* cBy  = cv + 24576;
  float* cEmb = cv + 32768;
  float* cWc  = cv + 33888;
  float* cbc  = cv + 33952;
  float* cWm  = cv + 33984;
  float* cbm  = cv + 38080;
  float* cW1  = cv + 38144;
  float* cA1  = cv + 54528;
  unsigned short* cW2T = (unsigned short*)(cv + 55040);  // 128 KB bf16 transposed
  float* cA2  = cv + 120576;
  int*   cPl  = (int*)(cv + 121088);

  bool ws_ok = (ws_size >= 8160 * sizeof(int));
  int* cSt = ws_ok ? (int*)d_ws : nullptr;

  ConvArgs a;
  a.src[0]  = d_in[2];        a.dst[0]  = cAx;  a.n[0]  = 8192;  a.kind[0]  = 0;
  a.src[1]  = d_in[3];        a.dst[1]  = cAy;  a.n[1]  = 8192;  a.kind[1]  = 0;
  a.src[2]  = d_in[4];        a.dst[2]  = cBx;  a.n[2]  = 8192;  a.kind[2]  = 0;
  a.src[3]  = d_in[5];        a.dst[3]  = cBy;  a.n[3]  = 8192;  a.kind[3]  = 0;
  a.src[4]  = d_in[base + 0]; a.dst[4]  = cEmb; a.n[4]  = 1120;  a.kind[4]  = 0;
  a.src[5]  = d_in[base + 1]; a.dst[5]  = cWc;  a.n[5]  = 64;    a.kind[5]  = 0;
  a.src[6]  = d_in[base + 2]; a.dst[6]  = cbc;  a.n[6]  = 32;    a.kind[6]  = 0;
  a.src[7]  = d_in[base + 3]; a.dst[7]  = cWm;  a.n[7]  = 4096;  a.kind[7]  = 0;
  a.src[8]  = d_in[base + 4]; a.dst[8]  = cbm;  a.n[8]  = 64;    a.kind[8]  = 0;
  a.src[9]  = d_in[base + 5]; a.dst[9]  = cW1;  a.n[9]  = 16384; a.kind[9]  = 0;
  a.src[10] = d_in[base + 6]; a.dst[10] = cA1;  a.n[10] = 512;   a.kind[10] = 0;
  a.src[11] = d_in[base + 7]; a.dst[11] = cW2T; a.n[11] = 65536; a.kind[11] = 2;
  a.src[12] = d_in[base + 8]; a.dst[12] = cA2;  a.n[12] = 512;   a.kind[12] = 0;
  a.src[13] = d_in[0];        a.dst[13] = cPl;  a.n[13] = 64;    a.kind[13] = 1;
  a.src[14] = d_in[1];        a.dst[14] = ws_ok ? (void*)cSt : (void*)cPl;
  a.n[14] = ws_ok ? 8160 : 0; a.kind[14] = 1;

  k_conv2<<<dim3(64, 15), 256, 0, stream>>>(a, (const unsigned*)d_in[base + 3],
                                            (const unsigned*)d_in[0]);

  k_feat3<<<BN, 64, 0, stream>>>(cPl, cAx, cAy, cBx, cBy, cEmb, cWc, cbc, cWm, cbm, x);

  // ---- layer 1 ----
  k_gemm<<<dim3(BN / 64, 4), 256, 0, stream>>>(x, cW1, h, 64, cA1, ss, sd);
  k_attn_mfma3<1><<<B_ * 4 * (N_ / 64), 256, 0, stream>>>(h, ss, sd, x2b);

  // ---- layer 2 ----
  k_gemm2_mfma<<<dim3(BN / 64, 4), 256, 0, stream>>>(x2b, cW2T, h, cA2, ss, sd);
  k_attn_mfma3<0><<<B_ * 4 * (N_ / 64), 256, 0, stream>>>(h, ss, sd, out_node);

  // ---- adjacency last (scratch lives in its output region) ----
  if (ws_ok) {
    k_adjf2<<<(ADJ_ELEMS / 4) / 256, 256, 0, stream>>>(cSt, out_adjf);
  } else {
    k_adjf<<<(ADJ_ELEMS / 4) / 256, 256, 0, stream>>>((const unsigned*)d_in[1], out_adjf);
  }

  if (mismatch >= 0) {
    float v = ldexpf(1024.f, mismatch);
    k_sentinel<<<1, 64, 0, stream>>>(out_node, v);
  }
}